// Round 4
// baseline (1357.088 us; speedup 1.0000x reference)
//
#include <hip/hip_runtime.h>
#include <hip/hip_bf16.h>
#include <math.h>

#define Cdim 512
#define Hn   8
#define HDim 64
#define Ld   4
#define Tn   1024
#define Bn   2
#define NTOK 2048   // B*T
#define FF   2048   // 4*C
#define Vn   32000

typedef __bf16 bf16_t;
typedef __bf16 bf16x8 __attribute__((ext_vector_type(8)));
typedef __bf16 bf16x4 __attribute__((ext_vector_type(4)));
typedef float  f32x4  __attribute__((ext_vector_type(4)));

// ---------------- embedding: out[b,t,:] = tok[inp[b,t],:] + pos[t,:] (f32) ----------------
__global__ __launch_bounds__(256) void embed_k(const int* __restrict__ inp,
    const float* __restrict__ tok, const float* __restrict__ pos,
    float* __restrict__ out)
{
    int idx = blockIdx.x * 256 + threadIdx.x;   // over B*T*C
    int c  = idx & (Cdim - 1);
    int bt = idx >> 9;
    int t  = bt & (Tn - 1);
    out[idx] = tok[(long)inp[bt] * Cdim + c] + pos[t * Cdim + c];
}

// ---------------- layernorm row body (C=512), 256 threads ----------------
__device__ __forceinline__ void ln_row(const float* __restrict__ xr,
    const float* __restrict__ g, const float* __restrict__ bb,
    bf16_t* __restrict__ yr, float* red, int tid)
{
    float v0 = xr[tid], v1 = xr[tid + 256];
    float s = v0 + v1;
    #pragma unroll
    for (int o = 32; o > 0; o >>= 1) s += __shfl_down(s, o, 64);
    int wid = tid >> 6, lane = tid & 63;
    if (lane == 0) red[wid] = s;
    __syncthreads();
    float mean = (red[0] + red[1] + red[2] + red[3]) * (1.f / Cdim);
    __syncthreads();
    float d0 = v0 - mean, d1 = v1 - mean;
    float qv = d0 * d0 + d1 * d1;
    #pragma unroll
    for (int o = 32; o > 0; o >>= 1) qv += __shfl_down(qv, o, 64);
    if (lane == 0) red[wid] = qv;
    __syncthreads();
    float var = (red[0] + red[1] + red[2] + red[3]) * (1.f / Cdim);
    float inv = rsqrtf(var + 1e-5f);
    yr[tid]       = (bf16_t)(d0 * inv * g[tid]       + bb[tid]);
    yr[tid + 256] = (bf16_t)(d1 * inv * g[tid + 256] + bb[tid + 256]);
}

__global__ __launch_bounds__(256) void ln_k(const float* __restrict__ x,
    const float* __restrict__ g, const float* __restrict__ bb,
    bf16_t* __restrict__ y)
{
    __shared__ float red[4];
    int row = blockIdx.x;
    ln_row(x + (long)row * Cdim, g, bb, y + (long)row * Cdim, red, threadIdx.x);
}

// two-source LN (cross-attention): rows < NTOK from x1->y1, else x2->y2 (same g,b)
__global__ __launch_bounds__(256) void ln2_k(const float* __restrict__ x1,
    const float* __restrict__ x2, const float* __restrict__ g,
    const float* __restrict__ bb, bf16_t* __restrict__ y1, bf16_t* __restrict__ y2)
{
    __shared__ float red[4];
    int row = blockIdx.x;
    const float* x = (row < NTOK) ? x1 : x2;
    bf16_t*      y = (row < NTOK) ? y1 : y2;
    int r = row & (NTOK - 1);
    ln_row(x + (long)r * Cdim, g, bb, y + (long)r * Cdim, red, threadIdx.x);
}

// ---------------- f32 -> bf16 elementwise convert ----------------
__global__ __launch_bounds__(256) void cvt_k(const float* __restrict__ x, bf16_t* __restrict__ y)
{
    int i = blockIdx.x * 256 + threadIdx.x;
    y[i] = (bf16_t)x[i];
}

// ------- tiled transpose+convert: f32 [R,Cc] -> bf16 [Cc,R]; two-level batch (zb,zh) -------
__global__ __launch_bounds__(256) void tcvt_k(const float* __restrict__ in,
    bf16_t* __restrict__ outp, int R, int Cc,
    long inOffB, long inOffH, long outOffB, long outOffH, int HB)
{
    int bz = blockIdx.z; int zb = bz / HB, zh = bz - zb * HB;
    in   += zb * inOffB  + zh * inOffH;
    outp += zb * outOffB + zh * outOffH;
    __shared__ float t[64][65];
    int r0 = blockIdx.y * 64, c0 = blockIdx.x * 64;
    int tx = threadIdx.x & 63, ty = threadIdx.x >> 6;
    #pragma unroll
    for (int i = 0; i < 16; i++)
        t[ty + i * 4][tx] = in[(long)(r0 + ty + i * 4) * Cc + c0 + tx];
    __syncthreads();
    #pragma unroll
    for (int i = 0; i < 16; i++) {
        int cc = ty + i * 4;
        outp[(long)(c0 + cc) * R + r0 + tx] = (bf16_t)t[tx][cc];
    }
}

// ------- fused QKV weight prep: 9 (set,part) sources in one launch -------
struct QkvSrc { const float* p[9]; };
// z: si = z>>5 (0..8: set*3+part), zb = (z>>3)&3 (layer), zh = z&7 (head)
__global__ __launch_bounds__(256) void tcvt_qkv_k(QkvSrc srcs, bf16_t* __restrict__ outp)
{
    int z = blockIdx.z;
    int si = z >> 5, zb = (z >> 3) & 3, zh = z & 7;
    int set = si / 3, part = si - set * 3;
    const float* in = srcs.p[si] + (long)zb * (Hn * Cdim * HDim) + (long)zh * (Cdim * HDim);
    bf16_t* op = outp + ((long)set * Ld + zb) * (1536L * Cdim)
                      + (long)part * 512 * Cdim + (long)zh * 64 * Cdim;
    __shared__ float t[64][65];
    int r0 = blockIdx.y * 64;
    int tx = threadIdx.x & 63, ty = threadIdx.x >> 6;
    #pragma unroll
    for (int i = 0; i < 16; i++)
        t[ty + i * 4][tx] = in[(long)(r0 + ty + i * 4) * HDim + tx];
    __syncthreads();
    #pragma unroll
    for (int i = 0; i < 16; i++) {
        int cc = ty + i * 4;
        op[(long)cc * Cdim + r0 + tx] = (bf16_t)t[tx][cc];
    }
}

// ================= bf16 MFMA GEMM: C = op(A @ Bt^T) =================
// A [M,K] bf16 row-major (lda), Bt [N,K] bf16 row-major (ldb).
// BM x BN tile, BK=32, 256 threads = 4 waves (2x2), 16x16x32 MFMA.
// global_load_lds width-16 staging, linear LDS. Batched via blockIdx.z -> (zb,zh).
// VOUT: output columns >= vSplit scattered transposed into vt.
// SWZM>0: XCD-aware column-major tile remap (SWZM = # of M tiles; grid product % 8 == 0).
template<int BM, int BN, bool BIAS, bool RELU, bool RES, bool OBF, bool VOUT, int SWZM>
__global__ __launch_bounds__(256) void mgemm_k(
    const bf16_t* __restrict__ A, const bf16_t* __restrict__ Bt,
    const float* __restrict__ bias, const float* __restrict__ res,
    void* __restrict__ Cout, bf16_t* __restrict__ vtout, int vSplit,
    int K, int lda, int ldb, int ldc,
    long aOffB, long aOffH, long bOffB, long bOffH, long cOffB, long cOffH, int HB)
{
    int bz = blockIdx.z;
    int zb = bz / HB, zh = bz - zb * HB;
    A  += zb * aOffB + zh * aOffH;
    Bt += zb * bOffB + zh * bOffH;
    long coff = zb * cOffB + zh * cOffH;

    constexpr int MR = BM / 32;     // 16x16 m-frags per wave
    constexpr int NR = BN / 32;
    __shared__ bf16_t As[BM * 32];
    __shared__ bf16_t Bs[BN * 32];

    int tid = threadIdx.x;
    int wv = tid >> 6, lane = tid & 63;
    int bm, bn;
    if constexpr (SWZM > 0) {
        int lin = blockIdx.y * gridDim.x + blockIdx.x;
        int tot = gridDim.x * gridDim.y;
        int chunk = tot >> 3;
        int e = (lin & 7) * chunk + (lin >> 3);   // bijective (tot % 8 == 0)
        bm = (e % SWZM) * BM;                     // column-major: same-bn tiles contiguous per XCD
        bn = (e / SWZM) * BN;
    } else {
        bm = blockIdx.y * BM; bn = blockIdx.x * BN;
    }
    int wr = wv >> 1, wc = wv & 1;

    f32x4 acc[MR][NR];
    #pragma unroll
    for (int i = 0; i < MR; i++)
        #pragma unroll
        for (int j = 0; j < NR; j++)
            acc[i][j] = (f32x4){0.f, 0.f, 0.f, 0.f};

    const int srow  = lane >> 2;        // 0..15 within a 16-row staging slab
    const int scol8 = (lane & 3) * 8;   // bf16 element offset within row
    const int r16 = lane & 15, kg8 = (lane >> 4) * 8;

    for (int k0 = 0; k0 < K; k0 += 32) {
        #pragma unroll
        for (int j = 0; j < BM / 64; j++) {
            int rbase = wv * (BM / 4) + j * 16;
            const bf16_t* g = A + (long)(bm + rbase + srow) * lda + (k0 + scol8);
            __builtin_amdgcn_global_load_lds(
                (const __attribute__((address_space(1))) void*)g,
                (__attribute__((address_space(3))) void*)&As[rbase * 32],
                16, 0, 0);
        }
        #pragma unroll
        for (int j = 0; j < BN / 64; j++) {
            int rbase = wv * (BN / 4) + j * 16;
            const bf16_t* g = Bt + (long)(bn + rbase + srow) * ldb + (k0 + scol8);
            __builtin_amdgcn_global_load_lds(
                (const __attribute__((address_space(1))) void*)g,
                (__attribute__((address_space(3))) void*)&Bs[rbase * 32],
                16, 0, 0);
        }
        __syncthreads();

        bf16x8 af[MR], bfv[NR];
        #pragma unroll
        for (int i = 0; i < MR; i++)
            af[i] = *(const bf16x8*)&As[(wr * (BM / 2) + i * 16 + r16) * 32 + kg8];
        #pragma unroll
        for (int j = 0; j < NR; j++)
            bfv[j] = *(const bf16x8*)&Bs[(wc * (BN / 2) + j * 16 + r16) * 32 + kg8];
        #pragma unroll
        for (int i = 0; i < MR; i++)
            #pragma unroll
            for (int j = 0; j < NR; j++)
                acc[i][j] = __builtin_amdgcn_mfma_f32_16x16x32_bf16(af[i], bfv[j], acc[i][j], 0, 0, 0);
        __syncthreads();
    }

    // ---- epilogue: C/D layout col=lane&15, row=(lane>>4)*4+q ----
    int crow0 = (lane >> 4) * 4;
    int ccol  = lane & 15;
    #pragma unroll
    for (int i = 0; i < MR; i++) {
        #pragma unroll
        for (int j = 0; j < NR; j++) {
            int gr = bm + wr * (BM / 2) + i * 16 + crow0;
            int gc = bn + wc * (BN / 2) + j * 16 + ccol;
            float bv = BIAS ? bias[gc] : 0.f;
            #pragma unroll
            for (int q = 0; q < 4; q++) {
                float v = acc[i][j][q];
                if (BIAS) v += bv;
                if (RELU) v = fmaxf(v, 0.f);
                if (VOUT && gc >= vSplit) {
                    int row = gr + q;
                    int b = row >> 10, t = row & (Tn - 1);
                    vtout[((long)b * 512 + (gc - vSplit)) * Tn + t] = (bf16_t)v;
                } else {
                    long oidx = coff + (long)(gr + q) * ldc + gc;
                    if (RES)  v += res[oidx];
                    if (OBF) ((bf16_t*)Cout)[oidx] = (bf16_t)v;
                    else     ((float*) Cout)[oidx] = v;
                }
            }
        }
    }
}

// ================= fused flash attention (KVBLK=128) =================
// grid: (T/64 q-tiles, B*H). 256 threads = 4 waves; wave w owns q-rows w*16..w*16+15.
// Q in regs; K [128][64] and V^T [64][128] staged reg->LDS; online softmax in regs
// with defer-max (THR=8); P bounced through per-wave LDS to A-frag layout.
template<bool CAUSAL, bool HASMASK>
__global__ __launch_bounds__(256) void flash_k(
    const bf16_t* __restrict__ qkv, const bf16_t* __restrict__ vt,
    const int* __restrict__ mask, bf16_t* __restrict__ ao)
{
    __shared__ bf16_t Kl[128][72];
    __shared__ bf16_t Vl[64][136];
    __shared__ bf16_t Pl[4][16][136];

    int qt = blockIdx.x, bh = blockIdx.y;
    int b = bh >> 3, h = bh & 7;
    int tid = threadIdx.x, wv = tid >> 6, lane = tid & 63;
    int r16 = lane & 15, g4 = lane >> 4;

    int qrow_blk = qt * 64 + wv * 16;
    const bf16_t* qb = qkv + ((long)(b * Tn + qrow_blk + r16)) * 1536 + h * 64;
    bf16x8 aq0 = *(const bf16x8*)&qb[g4 * 8];
    bf16x8 aq1 = *(const bf16x8*)&qb[32 + g4 * 8];

    f32x4 acc[4];
    #pragma unroll
    for (int j = 0; j < 4; j++) acc[j] = (f32x4){0.f, 0.f, 0.f, 0.f};
    float m_[4], l_[4];
    #pragma unroll
    for (int q = 0; q < 4; q++) { m_[q] = -1e30f; l_[q] = 0.f; }

    int nt = CAUSAL ? ((qt >> 1) + 1) : (Tn / 128);
    int krow = tid >> 3, kcol = (tid & 7) * 8;     // K stage: 32 rows/pass
    int vrow = tid >> 4, vcol = (tid & 15) * 8;    // V stage: 16 rows/pass

    for (int it = 0; it < nt; it++) {
        int s0 = it * 128;
        bf16x8 kr[4], vr[4];
        #pragma unroll
        for (int i = 0; i < 4; i++)
            kr[i] = *(const bf16x8*)&qkv[((long)(b * Tn + s0 + krow + i * 32)) * 1536 + 512 + h * 64 + kcol];
        #pragma unroll
        for (int i = 0; i < 4; i++)
            vr[i] = *(const bf16x8*)&vt[((long)(bh * 64 + vrow + i * 16)) * Tn + s0 + vcol];
        int mv0 = 0, mv1 = 0;
        if (HASMASK) { mv0 = mask[b * Tn + s0 + lane]; mv1 = mask[b * Tn + s0 + 64 + lane]; }
        __syncthreads();                     // prior tile fully consumed
        #pragma unroll
        for (int i = 0; i < 4; i++) *(bf16x8*)&Kl[krow + i * 32][kcol] = kr[i];
        #pragma unroll
        for (int i = 0; i < 4; i++) *(bf16x8*)&Vl[vrow + i * 16][vcol] = vr[i];
        __syncthreads();                     // tiles visible

        // ---- QK^T: 16 MFMA ----
        f32x4 sc[8];
        __builtin_amdgcn_s_setprio(1);
        #pragma unroll
        for (int j = 0; j < 8; j++) {
            sc[j] = (f32x4){0.f, 0.f, 0.f, 0.f};
            bf16x8 bk0 = *(const bf16x8*)&Kl[j * 16 + r16][g4 * 8];
            bf16x8 bk1 = *(const bf16x8*)&Kl[j * 16 + r16][32 + g4 * 8];
            sc[j] = __builtin_amdgcn_mfma_f32_16x16x32_bf16(aq0, bk0, sc[j], 0, 0, 0);
            sc[j] = __builtin_amdgcn_mfma_f32_16x16x32_bf16(aq1, bk1, sc[j], 0, 0, 0);
        }
        __builtin_amdgcn_s_setprio(0);

        // ---- scale + mask ----
        bool diag = CAUSAL && (it == (qt >> 1));
        #pragma unroll
        for (int j = 0; j < 8; j++) {
            int mm = 1;
            if (HASMASK) mm = __shfl((j < 4) ? mv0 : mv1, (j & 3) * 16 + r16, 64);
            #pragma unroll
            for (int q = 0; q < 4; q++) {
                float v = sc[j][q] * 0.125f;
                if (diag) {
                    int qr = (qt & 1) * 64 + wv * 16 + g4 * 4 + q;
                    if (j * 16 + r16 > qr) v = -1e30f;
                }
                if (HASMASK && mm == 0) v = -1e30f;
                sc[j][q] = v;
            }
        }

        // ---- online softmax, defer-max THR=8 ----
        float pmax[4];
        #pragma unroll
        for (int q = 0; q < 4; q++) {
            float v = sc[0][q];
            #pragma unroll
            for (int j = 1; j < 8; j++) v = fmaxf(v, sc[j][q]);
            v = fmaxf(v, __shfl_xor(v, 1, 64));
            v = fmaxf(v, __shfl_xor(v, 2, 64));
            v = fmaxf(v, __shfl_xor(v, 4, 64));
            v = fmaxf(v, __shfl_xor(v, 8, 64));
            pmax[q] = v;
        }
        bool skip = __all(pmax[0] <= m_[0] + 8.f && pmax[1] <= m_[1] + 8.f &&
                          pmax[2] <= m_[2] + 8.f && pmax[3] <= m_[3] + 8.f);
        if (!skip) {
            #pragma unroll
            for (int q = 0; q < 4; q++) {
                float mnew = fmaxf(m_[q], pmax[q]);
                float rf = __expf(m_[q] - mnew);
                l_[q] *= rf;
                #pragma unroll
                for (int j = 0; j < 4; j++) acc[j][q] *= rf;
                m_[q] = mnew;
            }
        }
        #pragma unroll
        for (int q = 0; q < 4; q++) {
            float rs = 0.f;
            #pragma unroll
            for (int j = 0; j < 8; j++) {
                float pv = __expf(sc[j][q] - m_[q]);
                sc[j][q] = pv;
                rs += pv;
            }
            rs += __shfl_xor(rs, 1, 64);
            rs += __shfl_xor(rs, 2, 64);
            rs += __shfl_xor(rs, 4, 64);
            rs += __shfl_xor(rs, 8, 64);
            l_[q] += rs;
        }

        // ---- P -> per-wave LDS (C/D layout -> A-frag layout) ----
        #pragma unroll
        for (int j = 0; j < 8; j++)
            #pragma unroll
            for (int q = 0; q < 4; q++)
                Pl[wv][g4 * 4 + q][j * 16 + r16] = (bf16_t)sc[j][q];
        asm volatile("s_waitcnt lgkmcnt(0)" ::: "memory");
        __builtin_amdgcn_sched_barrier(0);

        // ---- PV: 16 MFMA ----
        __builtin_amdgcn_s_setprio(1);
        #pragma unroll
        for (int c = 0; c < 4; c++) {
            bf16x8 pa = *(const bf16x8*)&Pl[wv][r16][c * 32 + g4 * 8];
            #pragma unroll
            for (int j = 0; j < 4; j++) {
                bf16x8 bv = *(const bf16x8*)&Vl[j * 16 + r16][c * 32 + g4 * 8];
                acc[j] = __builtin_amdgcn_mfma_f32_16x16x32_bf16(pa, bv, acc[j], 0, 0, 0);
            }
        }
        __builtin_amdgcn_s_setprio(0);
    }

    // ---- epilogue: O /= l, write [t][h*64+d] bf16 ----
    bf16_t* aob = ao + ((long)(b * Tn + qrow_blk + g4 * 4)) * Cdim + h * 64;
    #pragma unroll
    for (int q = 0; q < 4; q++) {
        float inv = 1.f / l_[q];
        #pragma unroll
        for (int j = 0; j < 4; j++)
            aob[(long)q * Cdim + j * 16 + r16] = (bf16_t)(acc[j][q] * inv);
    }
}

// ================================ host orchestration ================================
static void run_attn(hipStream_t stream, const bf16_t* hq, const bf16_t* hkv,
    const bf16_t* wqkv, const float* bo, const bf16_t* wo_t,
    float* xres, const int* mask, bool causal, bool selfattn,
    bf16_t* qkv, bf16_t* vt, bf16_t* ao)
{
    dim3 blk(256);
    if (selfattn) {
        // fused qkv projection: N=1536, v-part scattered to vt (128^2 tiles, 192 blocks)
        mgemm_k<128,128,false,false,false,true,true,0><<<dim3(12, 16, 1), blk, 0, stream>>>(
            hq, wqkv, nullptr, nullptr, qkv, vt, 1024,
            Cdim, Cdim, Cdim, 1536, 0,0,0,0,0,0, 1);
    } else {
        // q proj (N=512, 64^2 -> 256 blocks)
        mgemm_k<64,64,false,false,false,true,false,0><<<dim3(8, 32, 1), blk, 0, stream>>>(
            hq, wqkv, nullptr, nullptr, qkv, nullptr, 1 << 30,
            Cdim, Cdim, Cdim, 1536, 0,0,0,0,0,0, 1);
        // kv proj (N=1024, 128^2 -> 128 blocks; writes qkv cols 512.. and vt)
        mgemm_k<128,128,false,false,false,true,true,0><<<dim3(8, 16, 1), blk, 0, stream>>>(
            hkv, wqkv + 512 * Cdim, nullptr, nullptr, qkv + 512, vt, 512,
            Cdim, Cdim, Cdim, 1536, 0,0,0,0,0,0, 1);
    }
    if (causal)
        flash_k<true,false><<<dim3(Tn / 64, Bn * Hn), blk, 0, stream>>>(qkv, vt, nullptr, ao);
    else
        flash_k<false,true><<<dim3(Tn / 64, Bn * Hn), blk, 0, stream>>>(qkv, vt, mask, ao);
    // out projection + bias + residual (f32, in place on xres)
    mgemm_k<64,64,true,false,true,false,false,0><<<dim3(8, 32, 1), blk, 0, stream>>>(
        ao, wo_t, bo, xres, xres, nullptr, 1 << 30,
        Cdim, Cdim, Cdim, Cdim, 0,0,0,0,0,0, 1);
}

extern "C" void kernel_launch(void* const* d_in, const int* in_sizes, int n_in,
                              void* d_out, int out_size, void* d_ws, size_t ws_size,
                              hipStream_t stream)
{
    (void)in_sizes; (void)n_in; (void)out_size; (void)ws_size;
    const int*   enc_inp  = (const int*)d_in[0];
    const int*   dec_inp  = (const int*)d_in[1];
    const int*   enc_mask = (const int*)d_in[2];
    const float* tok_emb  = (const float*)d_in[3];
    const float* pos_emb  = (const float*)d_in[4];
    const float* e_wq  = (const float*)d_in[5];
    const float* e_wk  = (const float*)d_in[6];
    const float* e_wv  = (const float*)d_in[7];
    const float* e_wo  = (const float*)d_in[8];
    const float* e_bo  = (const float*)d_in[9];
    const float* dsa_wq = (const float*)d_in[10];
    const float* dsa_wk = (const float*)d_in[11];
    const float* dsa_wv = (const float*)d_in[12];
    const float* dsa_wo = (const float*)d_in[13];
    const float* dsa_bo = (const float*)d_in[14];
    const float* dca_wq = (const float*)d_in[15];
    const float* dca_wk = (const float*)d_in[16];
    const float* dca_wv = (const float*)d_in[17];
    const float* dca_wo = (const float*)d_in[18];
    const float* dca_bo = (const float*)d_in[19];
    const float* e_ln1_g = (const float*)d_in[20];
    const float* e_ln1_b = (const float*)d_in[21];
    const float* e_ln2_g = (const float*)d_in[22];
    const float* e_ln2_b = (const float*)d_in[23];
    const float* d_ln1_g = (const float*)d_in[24];
    const float* d_ln1_b = (const float*)d_in[25];
    const float* d_ln2_g = (const float*)d_in[26];
    const float* d_ln2_b = (const float*)d_in[27];
    const float* d_ln3_g = (const float*)d_in[28];
    const float* d_ln3_b = (const float*)d_in[29];
    const float* e_w1 = (const float*)d_in[30];
    const float* e_b1 = (const float*)d_in[31];
    const float* e_w2 = (const float*)d_in[32];
    const float* e_b2 = (const float*)d_in[33];
    const float* d_w1 = (const float*)d_in[34];
    const float* d_b1 = (const float*)d_in[35];
    const float* d_w2 = (const float*)d_in[36];
    const float* d_b2 = (const float*)d_in[37];
    const float* out_w = (const float*)d_in[38];
    const float* out_b = (const float*)d_in[39];
    float* out = (float*)d_out;

    // -------- workspace carve (bytes) --------
    char* p = (char*)d_ws;
    auto takeB = [&](size_t bytes) { char* r = p; p += (bytes + 255) & ~(size_t)255; return r; };
    float*  x_enc = (float*)takeB(1048576ull * 4);
    float*  x_dec = (float*)takeB(1048576ull * 4);
    bf16_t* h     = (bf16_t*)takeB(1048576ull * 2);
    bf16_t* hk    = (bf16_t*)takeB(1048576ull * 2);
    bf16_t* qkv   = (bf16_t*)takeB(3145728ull * 2);
    bf16_t* vt    = (bf16_t*)takeB(1048576ull * 2);
    bf16_t* ao    = (bf16_t*)takeB(1048576ull * 2);
    bf16_t* xdb   = (bf16_t*)takeB(1048576ull * 2);
    bf16_t* mid   = (bf16_t*)takeB(4194304ull * 2);
    bf16_t* wqkv_t = (bf16_t*)takeB(12ull * 786432 * 2);
    bf16_t* wo_t   = (bf16_t*)takeB(12ull * 262144 * 2);
    bf16_t* w1_t   = (bf16_t*)takeB(8ull * 1048576 * 2);
    bf16_t* w2_t   = (bf16_t*)takeB(8ull * 1048576 * 2);
    bf16_t* outw_t = (bf16_t*)takeB(16384000ull * 2);

    dim3 blk(256);
    const long LQKV = 1536L * Cdim;             // 786432 per layer (fused, transposed)

    // ================= weight prep: transpose + convert to bf16 [N,K] =================
    QkvSrc qs;
    qs.p[0] = e_wq;   qs.p[1] = e_wk;   qs.p[2] = e_wv;
    qs.p[3] = dsa_wq; qs.p[4] = dsa_wk; qs.p[5] = dsa_wv;
    qs.p[6] = dca_wq; qs.p[7] = dca_wk; qs.p[8] = dca_wv;
    tcvt_qkv_k<<<dim3(1, 8, 288), blk, 0, stream>>>(qs, wqkv_t);
    const float* wosrc[3] = {e_wo, dsa_wo, dca_wo};
    for (int s = 0; s < 3; s++)
        tcvt_k<<<dim3(8, 8, 4), blk, 0, stream>>>(
            wosrc[s], wo_t + (long)s * Ld * Cdim * Cdim,
            Cdim, Cdim, (long)Cdim * Cdim, 0, (long)Cdim * Cdim, 0, 1);
    tcvt_k<<<dim3(32, 8, 4), blk, 0, stream>>>(e_w1, w1_t,             Cdim, FF, (long)Cdim * FF, 0, (long)Cdim * FF, 0, 1);
    tcvt_k<<<dim3(32, 8, 4), blk, 0, stream>>>(d_w1, w1_t + 4ull * Cdim * FF, Cdim, FF, (long)Cdim * FF, 0, (long)Cdim * FF, 0, 1);
    tcvt_k<<<dim3(8, 32, 4), blk, 0, stream>>>(e_w2, w2_t,             FF, Cdim, (long)FF * Cdim, 0, (long)FF * Cdim, 0, 1);
    tcvt_k<<<dim3(8, 32, 4), blk, 0, stream>>>(d_w2, w2_t + 4ull * FF * Cdim, FF, Cdim, (long)FF * Cdim, 0, (long)FF * Cdim, 0, 1);
    tcvt_k<<<dim3(500, 8, 1), blk, 0, stream>>>(out_w, outw_t, Cdim, Vn, 0, 0, 0, 0, 1);

    // ================= encoder =================
    embed_k<<<NTOK * Cdim / 256, blk, 0, stream>>>(enc_inp, tok_emb, pos_emb, x_enc);
    for (int l = 0; l < Ld; l++) {
        ln_k<<<NTOK, blk, 0, stream>>>(x_enc, e_ln1_g + l * Cdim, e_ln1_b + l * Cdim, h);
        run_attn(stream, h, h,
                 wqkv_t + (long)l * LQKV, e_bo + l * Cdim, wo_t + (long)l * Cdim * Cdim,
                 x_enc, enc_mask, /*causal=*/false, /*self=*/true, qkv, vt, ao);
        ln_k<<<NTOK, blk, 0, stream>>>(x_enc, e_ln2_g + l * Cdim, e_ln2_b + l * Cdim, h);
        mgemm_k<128,128,true,true,false,true,false,0><<<dim3(16, 16, 1), blk, 0, stream>>>(
            h, w1_t + (long)l * Cdim * FF, e_b1 + l * FF, nullptr, mid, nullptr, 1 << 30,
            Cdim, Cdim, Cdim, FF, 0,0,0,0,0,0, 1);
        mgemm_k<64,64,true,false,true,false,false,0><<<dim3(8, 32, 1), blk, 0, stream>>>(
            mid, w2_t + (long)l * FF * Cdim, e_b2 + l * Cdim, x_enc, x_enc, nullptr, 1 << 30,
            FF, FF, FF, Cdim, 0,0,0,0,0,0, 1);
    }
    // x_enc now holds enc_out

    // ================= decoder =================
    embed_k<<<NTOK * Cdim / 256, blk, 0, stream>>>(dec_inp, tok_emb, pos_emb, x_dec);
    for (int l = 0; l < Ld; l++) {
        // causal self-attention
        ln_k<<<NTOK, blk, 0, stream>>>(x_dec, d_ln1_g + l * Cdim, d_ln1_b + l * Cdim, h);
        run_attn(stream, h, h,
                 wqkv_t + (long)(Ld + l) * LQKV, dsa_bo + l * Cdim,
                 wo_t + (long)(Ld + l) * Cdim * Cdim,
                 x_dec, nullptr, /*causal=*/true, /*self=*/true, qkv, vt, ao);
        // cross-attention (same LN applied to x and enc_out) — one fused launch
        ln2_k<<<2 * NTOK, blk, 0, stream>>>(x_dec, x_enc,
            d_ln2_g + l * Cdim, d_ln2_b + l * Cdim, h, hk);
        run_attn(stream, h, hk,
                 wqkv_t + (long)(2 * Ld + l) * LQKV, dca_bo + l * Cdim,
                 wo_t + (long)(2 * Ld + l) * Cdim * Cdim,
                 x_dec, enc_mask, /*causal=*/false, /*self=*/false, qkv, vt, ao);
        // FFN
        ln_k<<<NTOK, blk, 0, stream>>>(x_dec, d_ln3_g + l * Cdim, d_ln3_b + l * Cdim, h);
        mgemm_k<128,128,true,true,false,true,false,0><<<dim3(16, 16, 1), blk, 0, stream>>>(
            h, w1_t + (long)(Ld + l) * Cdim * FF, d_b1 + l * FF, nullptr, mid, nullptr, 1 << 30,
            Cdim, Cdim, Cdim, FF, 0,0,0,0,0,0, 1);
        mgemm_k<64,64,true,false,true,false,false,0><<<dim3(8, 32, 1), blk, 0, stream>>>(
            mid, w2_t + (long)(Ld + l) * FF * Cdim, d_b2 + l * Cdim, x_dec, x_dec, nullptr, 1 << 30,
            FF, FF, FF, Cdim, 0,0,0,0,0,0, 1);
    }

    // ================= final logits (f32 out, XCD-swizzled) =================
    cvt_k<<<NTOK * Cdim / 256, blk, 0, stream>>>(x_dec, xdb);
    mgemm_k<128,128,true,false,false,false,false,16><<<dim3(250, 16, 1), blk, 0, stream>>>(
        xdb, outw_t, out_b, nullptr, out, nullptr, 1 << 30,
        Cdim, Cdim, Cdim, Vn, 0,0,0,0,0,0, 1);
}

// Round 5
// 1208.170 us; speedup vs baseline: 1.1233x; 1.1233x over previous
//
#include <hip/hip_runtime.h>
#include <hip/hip_bf16.h>
#include <math.h>

#define Cdim 512
#define Hn   8
#define HDim 64
#define Ld   4
#define Tn   1024
#define Bn   2
#define NTOK 2048   // B*T
#define FF   2048   // 4*C
#define Vn   32000

typedef __bf16 bf16_t;
typedef __bf16 bf16x8 __attribute__((ext_vector_type(8)));
typedef float  f32x4  __attribute__((ext_vector_type(4)));

// ---------------- LN core on two register values (C=512, 256 thr) ----------------
__device__ __forceinline__ void ln_core(float v0, float v1,
    const float* __restrict__ g, const float* __restrict__ bb,
    bf16_t* __restrict__ yr, float* red, int tid)
{
    float s = v0 + v1;
    #pragma unroll
    for (int o = 32; o > 0; o >>= 1) s += __shfl_down(s, o, 64);
    int wid = tid >> 6, lane = tid & 63;
    if (lane == 0) red[wid] = s;
    __syncthreads();
    float mean = (red[0] + red[1] + red[2] + red[3]) * (1.f / Cdim);
    __syncthreads();
    float d0 = v0 - mean, d1 = v1 - mean;
    float qv = d0 * d0 + d1 * d1;
    #pragma unroll
    for (int o = 32; o > 0; o >>= 1) qv += __shfl_down(qv, o, 64);
    if (lane == 0) red[wid] = qv;
    __syncthreads();
    float var = (red[0] + red[1] + red[2] + red[3]) * (1.f / Cdim);
    float inv = rsqrtf(var + 1e-5f);
    yr[tid]       = (bf16_t)(d0 * inv * g[tid]       + bb[tid]);
    yr[tid + 256] = (bf16_t)(d1 * inv * g[tid + 256] + bb[tid + 256]);
}

__global__ __launch_bounds__(256) void ln_k(const float* __restrict__ x,
    const float* __restrict__ g, const float* __restrict__ bb, bf16_t* __restrict__ y)
{
    __shared__ float red[4];
    int row = blockIdx.x, tid = threadIdx.x;
    const float* xr = x + (long)row * Cdim;
    ln_core(xr[tid], xr[tid + 256], g, bb, y + (long)row * Cdim, red, tid);
}

// two-source LN (cross-attention): rows < NTOK from x1->y1, else x2->y2 (same g,b)
__global__ __launch_bounds__(256) void ln2_k(const float* __restrict__ x1,
    const float* __restrict__ x2, const float* __restrict__ g,
    const float* __restrict__ bb, bf16_t* __restrict__ y1, bf16_t* __restrict__ y2)
{
    __shared__ float red[4];
    int row = blockIdx.x, tid = threadIdx.x;
    const float* x = (row < NTOK) ? x1 : x2;
    bf16_t*      y = (row < NTOK) ? y1 : y2;
    int r = row & (NTOK - 1);
    const float* xr = x + (long)r * Cdim;
    ln_core(xr[tid], xr[tid + 256], g, bb, y + (long)r * Cdim, red, tid);
}

// ---------------- fused embedding + first-layer LN ----------------
__global__ __launch_bounds__(256) void embed_ln_k(const int* __restrict__ inp,
    const float* __restrict__ tok, const float* __restrict__ pos,
    const float* __restrict__ g, const float* __restrict__ bb,
    float* __restrict__ x, bf16_t* __restrict__ y)
{
    __shared__ float red[4];
    int bt = blockIdx.x, tid = threadIdx.x;
    int t = bt & (Tn - 1);
    long toff = (long)inp[bt] * Cdim;
    float v0 = tok[toff + tid]       + pos[(long)t * Cdim + tid];
    float v1 = tok[toff + tid + 256] + pos[(long)t * Cdim + tid + 256];
    float* xr = x + (long)bt * Cdim;
    xr[tid] = v0; xr[tid + 256] = v1;
    ln_core(v0, v1, g, bb, y + (long)bt * Cdim, red, tid);
}

// ------- batched tiled transpose+convert: f32 [R,Cc] -> bf16 [Cc,R] over z sources/layers -------
struct Ptr3 { const float* p[3]; };
__global__ __launch_bounds__(256) void tcvt_b_k(Ptr3 srcs, bf16_t* __restrict__ dst,
    int R, int Cc, int lps, long dstStride)
{
    int z = blockIdx.z; int s = z / lps, l = z - s * lps;
    const float* in = srcs.p[s] + (long)l * R * Cc;
    bf16_t* op = dst + (long)z * dstStride;
    __shared__ float t[64][65];
    int r0 = blockIdx.y * 64, c0 = blockIdx.x * 64;
    int tx = threadIdx.x & 63, ty = threadIdx.x >> 6;
    #pragma unroll
    for (int i = 0; i < 16; i++)
        t[ty + i * 4][tx] = in[(long)(r0 + ty + i * 4) * Cc + c0 + tx];
    __syncthreads();
    #pragma unroll
    for (int i = 0; i < 16; i++) {
        int cc = ty + i * 4;
        op[(long)(c0 + cc) * R + r0 + tx] = (bf16_t)t[tx][cc];
    }
}

// ------- fused QKV weight prep: 9 (set,part) sources in one launch -------
struct QkvSrc { const float* p[9]; };
__global__ __launch_bounds__(256) void tcvt_qkv_k(QkvSrc srcs, bf16_t* __restrict__ outp)
{
    int z = blockIdx.z;
    int si = z >> 5, zb = (z >> 3) & 3, zh = z & 7;
    int set = si / 3, part = si - set * 3;
    const float* in = srcs.p[si] + (long)zb * (Hn * Cdim * HDim) + (long)zh * (Cdim * HDim);
    bf16_t* op = outp + ((long)set * Ld + zb) * (1536L * Cdim)
                      + (long)part * 512 * Cdim + (long)zh * 64 * Cdim;
    __shared__ float t[64][65];
    int r0 = blockIdx.y * 64;
    int tx = threadIdx.x & 63, ty = threadIdx.x >> 6;
    #pragma unroll
    for (int i = 0; i < 16; i++)
        t[ty + i * 4][tx] = in[(long)(r0 + ty + i * 4) * HDim + tx];
    __syncthreads();
    #pragma unroll
    for (int i = 0; i < 16; i++) {
        int cc = ty + i * 4;
        op[(long)cc * Cdim + r0 + tx] = (bf16_t)t[tx][cc];
    }
}

// ================= bf16 MFMA GEMM: C = op(Asel @ Bt^T) =================
// A [M,K] bf16 row-major (lda), Bt [N,K] bf16 row-major (ldb). BK=32/64.
// 256 threads = 4 waves (2x2). A-select: tiles with bn >= aSplit read A2.
// VOUT: cols >= vSplit scattered transposed into vt. XOUT: also write bf16 copy.
// SWZM>0: XCD-aware column-major tile remap (grid product % 8 == 0).
template<int BM, int BN, int BK, bool BIAS, bool RELU, bool RES, bool OBF,
         bool VOUT, int SWZM, bool XOUT>
__global__ __launch_bounds__(256) void mgemm_k(
    const bf16_t* __restrict__ A, const bf16_t* __restrict__ A2, int aSplit,
    const bf16_t* __restrict__ Bt, const float* __restrict__ bias,
    const float* __restrict__ res, void* __restrict__ Cout,
    bf16_t* __restrict__ xout, bf16_t* __restrict__ vtout, int vSplit,
    int K, int lda, int ldb, int ldc)
{
    constexpr int MR = BM / 32;
    constexpr int NR = BN / 32;
    constexpr int KK = BK / 32;
    __shared__ bf16_t As[BM * BK];
    __shared__ bf16_t Bs[BN * BK];

    int tid = threadIdx.x;
    int wv = tid >> 6, lane = tid & 63;
    int bm, bn;
    if constexpr (SWZM > 0) {
        int lin = blockIdx.y * gridDim.x + blockIdx.x;
        int tot = gridDim.x * gridDim.y;
        int chunk = tot >> 3;
        int e = (lin & 7) * chunk + (lin >> 3);
        bm = (e % SWZM) * BM;
        bn = (e / SWZM) * BN;
    } else {
        bm = blockIdx.y * BM; bn = blockIdx.x * BN;
    }
    const bf16_t* Ab = (bn < aSplit) ? A : A2;
    int wr = wv >> 1, wc = wv & 1;

    f32x4 acc[MR][NR];
    #pragma unroll
    for (int i = 0; i < MR; i++)
        #pragma unroll
        for (int j = 0; j < NR; j++)
            acc[i][j] = (f32x4){0.f, 0.f, 0.f, 0.f};

    constexpr int LPR = BK / 8;     // lanes per LDS row
    constexpr int RPW = 512 / BK;   // rows per wave-chunk
    constexpr int RPP = 2048 / BK;  // rows per 256-thread pass
    const int sr  = lane / LPR;
    const int sc8 = (lane % LPR) * 8;
    const int r16 = lane & 15, kg8 = (lane >> 4) * 8;

    for (int k0 = 0; k0 < K; k0 += BK) {
        #pragma unroll
        for (int p = 0; p < BM * BK / 2048; p++) {
            int rb = p * RPP + wv * RPW;
            const bf16_t* g = Ab + (long)(bm + rb + sr) * lda + (k0 + sc8);
            __builtin_amdgcn_global_load_lds(
                (const __attribute__((address_space(1))) void*)g,
                (__attribute__((address_space(3))) void*)&As[rb * BK],
                16, 0, 0);
        }
        #pragma unroll
        for (int p = 0; p < BN * BK / 2048; p++) {
            int rb = p * RPP + wv * RPW;
            const bf16_t* g = Bt + (long)(bn + rb + sr) * ldb + (k0 + sc8);
            __builtin_amdgcn_global_load_lds(
                (const __attribute__((address_space(1))) void*)g,
                (__attribute__((address_space(3))) void*)&Bs[rb * BK],
                16, 0, 0);
        }
        __syncthreads();

        bf16x8 af[MR][KK], bfv[NR][KK];
        #pragma unroll
        for (int i = 0; i < MR; i++)
            #pragma unroll
            for (int kk = 0; kk < KK; kk++)
                af[i][kk] = *(const bf16x8*)&As[(wr * (BM / 2) + i * 16 + r16) * BK + kk * 32 + kg8];
        #pragma unroll
        for (int j = 0; j < NR; j++)
            #pragma unroll
            for (int kk = 0; kk < KK; kk++)
                bfv[j][kk] = *(const bf16x8*)&Bs[(wc * (BN / 2) + j * 16 + r16) * BK + kk * 32 + kg8];
        #pragma unroll
        for (int kk = 0; kk < KK; kk++)
            #pragma unroll
            for (int i = 0; i < MR; i++)
                #pragma unroll
                for (int j = 0; j < NR; j++)
                    acc[i][j] = __builtin_amdgcn_mfma_f32_16x16x32_bf16(af[i][kk], bfv[j][kk], acc[i][j], 0, 0, 0);
        __syncthreads();
    }

    // ---- epilogue: C/D layout col=lane&15, row=(lane>>4)*4+q ----
    int crow0 = (lane >> 4) * 4;
    int ccol  = lane & 15;
    #pragma unroll
    for (int i = 0; i < MR; i++) {
        #pragma unroll
        for (int j = 0; j < NR; j++) {
            int gr = bm + wr * (BM / 2) + i * 16 + crow0;
            int gc = bn + wc * (BN / 2) + j * 16 + ccol;
            float bv = BIAS ? bias[gc] : 0.f;
            #pragma unroll
            for (int q = 0; q < 4; q++) {
                float v = acc[i][j][q];
                if (BIAS) v += bv;
                if (RELU) v = fmaxf(v, 0.f);
                if (VOUT && gc >= vSplit) {
                    int row = gr + q;
                    int b = row >> 10, t = row & (Tn - 1);
                    vtout[((long)b * 512 + (gc - vSplit)) * Tn + t] = (bf16_t)v;
                } else {
                    long oidx = (long)(gr + q) * ldc + gc;
                    if (RES)  v += res[oidx];
                    if (OBF) ((bf16_t*)Cout)[oidx] = (bf16_t)v;
                    else     ((float*) Cout)[oidx] = v;
                    if (XOUT) xout[oidx] = (bf16_t)v;
                }
            }
        }
    }
}

// ================= fused flash attention (8 waves, KV-split even/odd) =================
// grid (T/64, B*H), 512 threads. Waves 0-3 (group 0) take even KV tiles, 4-7 odd,
// over the SAME 64 q-rows; states merged at the end via LDS.
template<bool CAUSAL, bool HASMASK>
__global__ __launch_bounds__(512, 2) void flash_k(
    const bf16_t* __restrict__ qkv, const bf16_t* __restrict__ vt,
    const int* __restrict__ mask, bf16_t* __restrict__ ao)
{
    __shared__ bf16_t Kl[2][64][72];
    __shared__ bf16_t Vl[2][64][72];
    __shared__ bf16_t Pl[8][16][72];

    int qt = blockIdx.x, bh = blockIdx.y;
    int b = bh >> 3, h = bh & 7;
    int tid = threadIdx.x, wv = tid >> 6, lane = tid & 63;
    int wg = wv >> 2, wq4 = wv & 3;
    int r16 = lane & 15, g4 = lane >> 4;
    int gtid = tid & 255;

    const bf16_t* qb = qkv + ((long)(b * Tn + qt * 64 + wq4 * 16 + r16)) * 1536 + h * 64;
    bf16x8 aq0 = *(const bf16x8*)&qb[g4 * 8];
    bf16x8 aq1 = *(const bf16x8*)&qb[32 + g4 * 8];

    f32x4 acc[4];
    #pragma unroll
    for (int j = 0; j < 4; j++) acc[j] = (f32x4){0.f, 0.f, 0.f, 0.f};
    float m_[4], l_[4];
    #pragma unroll
    for (int q = 0; q < 4; q++) { m_[q] = -1e30f; l_[q] = 0.f; }

    int lastT = CAUSAL ? qt : (Tn / 64 - 1);
    int niter = CAUSAL ? (qt / 2 + 1) : (Tn / 128);
    int krow = gtid >> 3, kcol = (gtid & 7) * 8;   // 32 rows/pass, 2 passes

    for (int it = 0; it < niter; it++) {
        int t = 2 * it + wg;
        bool active = t <= lastT;
        int s0 = t * 64;
        bf16x8 kr[2], vr[2];
        int mv = 0;
        if (active) {
            #pragma unroll
            for (int i = 0; i < 2; i++)
                kr[i] = *(const bf16x8*)&qkv[((long)(b * Tn + s0 + krow + i * 32)) * 1536 + 512 + h * 64 + kcol];
            #pragma unroll
            for (int i = 0; i < 2; i++)
                vr[i] = *(const bf16x8*)&vt[((long)(bh * 64 + krow + i * 32)) * Tn + s0 + kcol];
            if (HASMASK) mv = mask[b * Tn + s0 + lane];
        }
        __syncthreads();                      // prior tile consumed
        if (active) {
            #pragma unroll
            for (int i = 0; i < 2; i++) *(bf16x8*)&Kl[wg][krow + i * 32][kcol] = kr[i];
            #pragma unroll
            for (int i = 0; i < 2; i++) *(bf16x8*)&Vl[wg][krow + i * 32][kcol] = vr[i];
        }
        __syncthreads();                      // tiles visible
        if (!active) continue;

        // ---- QK^T: 8 MFMA ----
        f32x4 scv[4];
        __builtin_amdgcn_s_setprio(1);
        #pragma unroll
        for (int j = 0; j < 4; j++) {
            scv[j] = (f32x4){0.f, 0.f, 0.f, 0.f};
            bf16x8 bk0 = *(const bf16x8*)&Kl[wg][j * 16 + r16][g4 * 8];
            bf16x8 bk1 = *(const bf16x8*)&Kl[wg][j * 16 + r16][32 + g4 * 8];
            scv[j] = __builtin_amdgcn_mfma_f32_16x16x32_bf16(aq0, bk0, scv[j], 0, 0, 0);
            scv[j] = __builtin_amdgcn_mfma_f32_16x16x32_bf16(aq1, bk1, scv[j], 0, 0, 0);
        }
        __builtin_amdgcn_s_setprio(0);

        // ---- scale + mask ----
        bool diag = CAUSAL && (t == qt);
        #pragma unroll
        for (int j = 0; j < 4; j++) {
            int col = j * 16 + r16;
            int mm = 1;
            if (HASMASK) mm = __shfl(mv, col, 64);
            #pragma unroll
            for (int q = 0; q < 4; q++) {
                float v = scv[j][q] * 0.125f;
                if (diag && col > wq4 * 16 + g4 * 4 + q) v = -1e30f;
                if (HASMASK && mm == 0) v = -1e30f;
                scv[j][q] = v;
            }
        }

        // ---- online softmax with defer-max (THR=8) ----
        float pmax[4];
        #pragma unroll
        for (int q = 0; q < 4; q++) {
            float v = fmaxf(fmaxf(scv[0][q], scv[1][q]), fmaxf(scv[2][q], scv[3][q]));
            v = fmaxf(v, __shfl_xor(v, 1, 64));
            v = fmaxf(v, __shfl_xor(v, 2, 64));
            v = fmaxf(v, __shfl_xor(v, 4, 64));
            v = fmaxf(v, __shfl_xor(v, 8, 64));
            pmax[q] = v;
        }
        bool skip = __all(pmax[0] <= m_[0] + 8.f && pmax[1] <= m_[1] + 8.f &&
                          pmax[2] <= m_[2] + 8.f && pmax[3] <= m_[3] + 8.f);
        if (!skip) {
            #pragma unroll
            for (int q = 0; q < 4; q++) {
                float mnew = fmaxf(m_[q], pmax[q]);
                float rf = __expf(m_[q] - mnew);
                l_[q] *= rf;
                #pragma unroll
                for (int j = 0; j < 4; j++) acc[j][q] *= rf;
                m_[q] = mnew;
            }
        }
        #pragma unroll
        for (int q = 0; q < 4; q++) {
            float rs = 0.f;
            #pragma unroll
            for (int j = 0; j < 4; j++) {
                float pv = __expf(scv[j][q] - m_[q]);
                scv[j][q] = pv;
                rs += pv;
            }
            rs += __shfl_xor(rs, 1, 64);
            rs += __shfl_xor(rs, 2, 64);
            rs += __shfl_xor(rs, 4, 64);
            rs += __shfl_xor(rs, 8, 64);
            l_[q] += rs;
        }

        // ---- P -> per-wave LDS (C/D layout -> A-frag layout) ----
        #pragma unroll
        for (int j = 0; j < 4; j++)
            #pragma unroll
            for (int q = 0; q < 4; q++)
                Pl[wv][g4 * 4 + q][j * 16 + r16] = (bf16_t)scv[j][q];
        asm volatile("s_waitcnt lgkmcnt(0)" ::: "memory");
        __builtin_amdgcn_sched_barrier(0);

        // ---- PV: 8 MFMA ----
        __builtin_amdgcn_s_setprio(1);
        #pragma unroll
        for (int c = 0; c < 2; c++) {
            bf16x8 pa = *(const bf16x8*)&Pl[wv][r16][c * 32 + g4 * 8];
            #pragma unroll
            for (int j = 0; j < 4; j++) {
                bf16x8 bv = *(const bf16x8*)&Vl[wg][j * 16 + r16][c * 32 + g4 * 8];
                acc[j] = __builtin_amdgcn_mfma_f32_16x16x32_bf16(pa, bv, acc[j], 0, 0, 0);
            }
        }
        __builtin_amdgcn_s_setprio(0);
    }

    // ---- merge group 1 state into group 0 via LDS, write output ----
    float* accS = (float*)&Kl[0][0][0];      // [64][64] f32 = 16 KB (fits in Kl)
    float* mlS  = accS + 64 * 64;            // [64][2]
    __syncthreads();
    if (wg == 1) {
        #pragma unroll
        for (int j = 0; j < 4; j++)
            #pragma unroll
            for (int q = 0; q < 4; q++)
                accS[(wq4 * 16 + g4 * 4 + q) * 64 + j * 16 + r16] = acc[j][q];
        if (r16 == 0)
            #pragma unroll
            for (int q = 0; q < 4; q++) {
                mlS[(wq4 * 16 + g4 * 4 + q) * 2 + 0] = m_[q];
                mlS[(wq4 * 16 + g4 * 4 + q) * 2 + 1] = l_[q];
            }
    }
    __syncthreads();
    if (wg == 0) {
        bf16_t* aob = ao + ((long)(b * Tn + qt * 64 + wq4 * 16 + g4 * 4)) * Cdim + h * 64;
        #pragma unroll
        for (int q = 0; q < 4; q++) {
            int row = wq4 * 16 + g4 * 4 + q;
            float mB = mlS[row * 2], lB = mlS[row * 2 + 1];
            float mS = fmaxf(m_[q], mB);
            float fA = __expf(m_[q] - mS), fB = __expf(mB - mS);
            float lS = l_[q] * fA + lB * fB;
            float inv = 1.f / lS;
            #pragma unroll
            for (int j = 0; j < 4; j++) {
                float o = (acc[j][q] * fA + accS[row * 64 + j * 16 + r16] * fB) * inv;
                aob[(long)q * Cdim + j * 16 + r16] = (bf16_t)o;
            }
        }
    }
}

// ================================ host orchestration ================================
static void run_attn(hipStream_t stream, const bf16_t* hq, const bf16_t* hkv,
    const bf16_t* wqkv, const float* bo, const bf16_t* wo_t,
    float* xres, const int* mask, bool causal,
    bf16_t* qkv, bf16_t* vt, bf16_t* ao)
{
    dim3 blk(256);
    // fused qkv projection: N=1536 (cols<512 read hq, else hkv); v-part -> vt
    mgemm_k<64,128,64,false,false,false,true,true,0,false><<<dim3(12, 32, 1), blk, 0, stream>>>(
        hq, hkv, 512, wqkv, nullptr, nullptr, qkv, nullptr, vt, 1024,
        Cdim, Cdim, Cdim, 1536);
    if (causal)
        flash_k<true,false><<<dim3(Tn / 64, Bn * Hn), dim3(512), 0, stream>>>(qkv, vt, nullptr, ao);
    else
        flash_k<false,true><<<dim3(Tn / 64, Bn * Hn), dim3(512), 0, stream>>>(qkv, vt, mask, ao);
    // out projection + bias + residual (f32, in place on xres)
    mgemm_k<64,64,64,true,false,true,false,false,0,false><<<dim3(8, 32, 1), blk, 0, stream>>>(
        ao, ao, 1 << 30, wo_t, bo, xres, xres, nullptr, nullptr, 1 << 30,
        Cdim, Cdim, Cdim, Cdim);
}

extern "C" void kernel_launch(void* const* d_in, const int* in_sizes, int n_in,
                              void* d_out, int out_size, void* d_ws, size_t ws_size,
                              hipStream_t stream)
{
    (void)in_sizes; (void)n_in; (void)out_size; (void)ws_size;
    const int*   enc_inp  = (const int*)d_in[0];
    const int*   dec_inp  = (const int*)d_in[1];
    const int*   enc_mask = (const int*)d_in[2];
    const float* tok_emb  = (const float*)d_in[3];
    const float* pos_emb  = (const float*)d_in[4];
    const float* e_wq  = (const float*)d_in[5];
    const float* e_wk  = (const float*)d_in[6];
    const float* e_wv  = (const float*)d_in[7];
    const float* e_wo  = (const float*)d_in[8];
    const float* e_bo  = (const float*)d_in[9];
    const float* dsa_wq = (const float*)d_in[10];
    const float* dsa_wk = (const float*)d_in[11];
    const float* dsa_wv = (const float*)d_in[12];
    const float* dsa_wo = (const float*)d_in[13];
    const float* dsa_bo = (const float*)d_in[14];
    const float* dca_wq = (const float*)d_in[15];
    const float* dca_wk = (const float*)d_in[16];
    const float* dca_wv = (const float*)d_in[17];
    const float* dca_wo = (const float*)d_in[18];
    const float* dca_bo = (const float*)d_in[19];
    const float* e_ln1_g = (const float*)d_in[20];
    const float* e_ln1_b = (const float*)d_in[21];
    const float* e_ln2_g = (const float*)d_in[22];
    const float* e_ln2_b = (const float*)d_in[23];
    const float* d_ln1_g = (const float*)d_in[24];
    const float* d_ln1_b = (const float*)d_in[25];
    const float* d_ln2_g = (const float*)d_in[26];
    const float* d_ln2_b = (const float*)d_in[27];
    const float* d_ln3_g = (const float*)d_in[28];
    const float* d_ln3_b = (const float*)d_in[29];
    const float* e_w1 = (const float*)d_in[30];
    const float* e_b1 = (const float*)d_in[31];
    const float* e_w2 = (const float*)d_in[32];
    const float* e_b2 = (const float*)d_in[33];
    const float* d_w1 = (const float*)d_in[34];
    const float* d_b1 = (const float*)d_in[35];
    const float* d_w2 = (const float*)d_in[36];
    const float* d_b2 = (const float*)d_in[37];
    const float* out_w = (const float*)d_in[38];
    const float* out_b = (const float*)d_in[39];
    float* out = (float*)d_out;

    // -------- workspace carve (bytes) --------
    char* p = (char*)d_ws;
    auto takeB = [&](size_t bytes) { char* r = p; p += (bytes + 255) & ~(size_t)255; return r; };
    float*  x_enc = (float*)takeB(1048576ull * 4);
    float*  x_dec = (float*)takeB(1048576ull * 4);
    bf16_t* h     = (bf16_t*)takeB(1048576ull * 2);
    bf16_t* hk    = (bf16_t*)takeB(1048576ull * 2);
    bf16_t* qkv   = (bf16_t*)takeB(3145728ull * 2);
    bf16_t* vt    = (bf16_t*)takeB(1048576ull * 2);
    bf16_t* ao    = (bf16_t*)takeB(1048576ull * 2);
    bf16_t* xdb   = (bf16_t*)takeB(1048576ull * 2);
    bf16_t* mid   = (bf16_t*)takeB(4194304ull * 2);
    bf16_t* wqkv_t = (bf16_t*)takeB(12ull * 786432 * 2);
    bf16_t* wo_t   = (bf16_t*)takeB(12ull * 262144 * 2);
    bf16_t* w1_t   = (bf16_t*)takeB(8ull * 1048576 * 2);
    bf16_t* w2_t   = (bf16_t*)takeB(8ull * 1048576 * 2);
    bf16_t* outw_t = (bf16_t*)takeB(16384000ull * 2);

    dim3 blk(256);
    const long LQKV = 1536L * Cdim;             // per-layer fused transposed qkv weights

    // ================= weight prep (5 launches) =================
    QkvSrc qs;
    qs.p[0] = e_wq;   qs.p[1] = e_wk;   qs.p[2] = e_wv;
    qs.p[3] = dsa_wq; qs.p[4] = dsa_wk; qs.p[5] = dsa_wv;
    qs.p[6] = dca_wq; qs.p[7] = dca_wk; qs.p[8] = dca_wv;
    tcvt_qkv_k<<<dim3(1, 8, 288), blk, 0, stream>>>(qs, wqkv_t);
    Ptr3 pw;
    pw.p[0] = e_wo; pw.p[1] = dsa_wo; pw.p[2] = dca_wo;
    tcvt_b_k<<<dim3(8, 8, 12), blk, 0, stream>>>(pw, wo_t, Cdim, Cdim, 4, (long)Cdim * Cdim);
    pw.p[0] = e_w1; pw.p[1] = d_w1; pw.p[2] = nullptr;
    tcvt_b_k<<<dim3(32, 8, 8), blk, 0, stream>>>(pw, w1_t, Cdim, FF, 4, (long)Cdim * FF);
    pw.p[0] = e_w2; pw.p[1] = d_w2; pw.p[2] = nullptr;
    tcvt_b_k<<<dim3(8, 32, 8), blk, 0, stream>>>(pw, w2_t, FF, Cdim, 4, (long)FF * Cdim);
    pw.p[0] = out_w; pw.p[1] = nullptr; pw.p[2] = nullptr;
    tcvt_b_k<<<dim3(500, 8, 1), blk, 0, stream>>>(pw, outw_t, Cdim, Vn, 1, 0);

    // ================= encoder =================
    embed_ln_k<<<NTOK, blk, 0, stream>>>(enc_inp, tok_emb, pos_emb, e_ln1_g, e_ln1_b, x_enc, h);
    for (int l = 0; l < Ld; l++) {
        if (l) ln_k<<<NTOK, blk, 0, stream>>>(x_enc, e_ln1_g + l * Cdim, e_ln1_b + l * Cdim, h);
        run_attn(stream, h, h,
                 wqkv_t + (long)l * LQKV, e_bo + l * Cdim, wo_t + (long)l * Cdim * Cdim,
                 x_enc, enc_mask, /*causal=*/false, qkv, vt, ao);
        ln_k<<<NTOK, blk, 0, stream>>>(x_enc, e_ln2_g + l * Cdim, e_ln2_b + l * Cdim, h);
        mgemm_k<128,128,64,true,true,false,true,false,0,false><<<dim3(16, 16, 1), blk, 0, stream>>>(
            h, h, 1 << 30, w1_t + (long)l * Cdim * FF, e_b1 + l * FF, nullptr, mid,
            nullptr, nullptr, 1 << 30, Cdim, Cdim, Cdim, FF);
        mgemm_k<64,64,64,true,false,true,false,false,0,false><<<dim3(8, 32, 1), blk, 0, stream>>>(
            mid, mid, 1 << 30, w2_t + (long)l * FF * Cdim, e_b2 + l * Cdim, x_enc, x_enc,
            nullptr, nullptr, 1 << 30, FF, FF, FF, Cdim);
    }
    // x_enc now holds enc_out

    // ================= decoder =================
    embed_ln_k<<<NTOK, blk, 0, stream>>>(dec_inp, tok_emb, pos_emb, d_ln1_g, d_ln1_b, x_dec, h);
    for (int l = 0; l < Ld; l++) {
        // causal self-attention
        if (l) ln_k<<<NTOK, blk, 0, stream>>>(x_dec, d_ln1_g + l * Cdim, d_ln1_b + l * Cdim, h);
        run_attn(stream, h, h,
                 wqkv_t + (long)(Ld + l) * LQKV, dsa_bo + l * Cdim,
                 wo_t + (long)(Ld + l) * Cdim * Cdim,
                 x_dec, nullptr, /*causal=*/true, qkv, vt, ao);
        // cross-attention (same LN applied to x and enc_out) — one fused launch
        ln2_k<<<2 * NTOK, blk, 0, stream>>>(x_dec, x_enc,
            d_ln2_g + l * Cdim, d_ln2_b + l * Cdim, h, hk);
        run_attn(stream, h, hk,
                 wqkv_t + (long)(2 * Ld + l) * LQKV, dca_bo + l * Cdim,
                 wo_t + (long)(2 * Ld + l) * Cdim * Cdim,
                 x_dec, enc_mask, /*causal=*/false, qkv, vt, ao);
        // FFN
        ln_k<<<NTOK, blk, 0, stream>>>(x_dec, d_ln3_g + l * Cdim, d_ln3_b + l * Cdim, h);
        mgemm_k<128,128,64,true,true,false,true,false,0,false><<<dim3(16, 16, 1), blk, 0, stream>>>(
            h, h, 1 << 30, w1_t + (long)(Ld + l) * Cdim * FF, d_b1 + l * FF, nullptr, mid,
            nullptr, nullptr, 1 << 30, Cdim, Cdim, Cdim, FF);
        if (l < Ld - 1)
            mgemm_k<64,64,64,true,false,true,false,false,0,false><<<dim3(8, 32, 1), blk, 0, stream>>>(
                mid, mid, 1 << 30, w2_t + (long)(Ld + l) * FF * Cdim, d_b2 + l * Cdim, x_dec, x_dec,
                nullptr, nullptr, 1 << 30, FF, FF, FF, Cdim);
        else  // last layer: also emit bf16 copy for logits GEMM
            mgemm_k<64,64,64,true,false,true,false,false,0,true><<<dim3(8, 32, 1), blk, 0, stream>>>(
                mid, mid, 1 << 30, w2_t + (long)(Ld + l) * FF * Cdim, d_b2 + l * Cdim, x_dec, x_dec,
                xdb, nullptr, 1 << 30, FF, FF, FF, Cdim);
    }

    // ================= final logits (f32 out, XCD-swizzled) =================
    mgemm_k<128,128,64,true,false,false,false,false,16,false><<<dim3(250, 16, 1), blk, 0, stream>>>(
        xdb, xdb, 1 << 30, outw_t, out_b, nullptr, out, nullptr, nullptr, 1 << 30,
        Cdim, Cdim, Cdim, Vn);
}

// Round 6
// 1159.975 us; speedup vs baseline: 1.1699x; 1.0415x over previous
//
#include <hip/hip_runtime.h>
#include <hip/hip_bf16.h>
#include <math.h>

#define Cdim 512
#define Hn   8
#define HDim 64
#define Ld   4
#define Tn   1024
#define Bn   2
#define NTOK 2048   // B*T
#define FF   2048   // 4*C
#define Vn   32000

typedef __bf16 bf16_t;
typedef __bf16 bf16x8 __attribute__((ext_vector_type(8)));
typedef float  f32x4  __attribute__((ext_vector_type(4)));

// ---------------- LN core on two register values (C=512, 256 thr) ----------------
__device__ __forceinline__ void ln_core(float v0, float v1,
    const float* __restrict__ g, const float* __restrict__ bb,
    bf16_t* __restrict__ yr, float* red, int tid)
{
    float s = v0 + v1;
    #pragma unroll
    for (int o = 32; o > 0; o >>= 1) s += __shfl_down(s, o, 64);
    int wid = tid >> 6, lane = tid & 63;
    if (lane == 0) red[wid] = s;
    __syncthreads();
    float mean = (red[0] + red[1] + red[2] + red[3]) * (1.f / Cdim);
    __syncthreads();
    float d0 = v0 - mean, d1 = v1 - mean;
    float qv = d0 * d0 + d1 * d1;
    #pragma unroll
    for (int o = 32; o > 0; o >>= 1) qv += __shfl_down(qv, o, 64);
    if (lane == 0) red[wid] = qv;
    __syncthreads();
    float var = (red[0] + red[1] + red[2] + red[3]) * (1.f / Cdim);
    float inv = rsqrtf(var + 1e-5f);
    yr[tid]       = (bf16_t)(d0 * inv * g[tid]       + bb[tid]);
    yr[tid + 256] = (bf16_t)(d1 * inv * g[tid + 256] + bb[tid + 256]);
}

__global__ __launch_bounds__(256) void ln_k(const float* __restrict__ x,
    const float* __restrict__ g, const float* __restrict__ bb, bf16_t* __restrict__ y)
{
    __shared__ float red[4];
    int row = blockIdx.x, tid = threadIdx.x;
    const float* xr = x + (long)row * Cdim;
    ln_core(xr[tid], xr[tid + 256], g, bb, y + (long)row * Cdim, red, tid);
}

// two-source LN (cross-attention): rows < NTOK from x1->y1, else x2->y2 (same g,b)
__global__ __launch_bounds__(256) void ln2_k(const float* __restrict__ x1,
    const float* __restrict__ x2, const float* __restrict__ g,
    const float* __restrict__ bb, bf16_t* __restrict__ y1, bf16_t* __restrict__ y2)
{
    __shared__ float red[4];
    int row = blockIdx.x, tid = threadIdx.x;
    const float* x = (row < NTOK) ? x1 : x2;
    bf16_t*      y = (row < NTOK) ? y1 : y2;
    int r = row & (NTOK - 1);
    const float* xr = x + (long)r * Cdim;
    ln_core(xr[tid], xr[tid + 256], g, bb, y + (long)r * Cdim, red, tid);
}

// ---------------- fused embedding + first-layer LN ----------------
__global__ __launch_bounds__(256) void embed_ln_k(const int* __restrict__ inp,
    const float* __restrict__ tok, const float* __restrict__ pos,
    const float* __restrict__ g, const float* __restrict__ bb,
    float* __restrict__ x, bf16_t* __restrict__ y)
{
    __shared__ float red[4];
    int bt = blockIdx.x, tid = threadIdx.x;
    int t = bt & (Tn - 1);
    long toff = (long)inp[bt] * Cdim;
    float v0 = tok[toff + tid]       + pos[(long)t * Cdim + tid];
    float v1 = tok[toff + tid + 256] + pos[(long)t * Cdim + tid + 256];
    float* xr = x + (long)bt * Cdim;
    xr[tid] = v0; xr[tid + 256] = v1;
    ln_core(v0, v1, g, bb, y + (long)bt * Cdim, red, tid);
}

// ------- batched tiled transpose+convert: f32 [R,Cc] -> bf16 [Cc,R] over z sources/layers -------
struct Ptr3 { const float* p[3]; };
__global__ __launch_bounds__(256) void tcvt_b_k(Ptr3 srcs, bf16_t* __restrict__ dst,
    int R, int Cc, int lps, long dstStride)
{
    int z = blockIdx.z; int s = z / lps, l = z - s * lps;
    const float* in = srcs.p[s] + (long)l * R * Cc;
    bf16_t* op = dst + (long)z * dstStride;
    __shared__ float t[64][65];
    int r0 = blockIdx.y * 64, c0 = blockIdx.x * 64;
    int tx = threadIdx.x & 63, ty = threadIdx.x >> 6;
    #pragma unroll
    for (int i = 0; i < 16; i++)
        t[ty + i * 4][tx] = in[(long)(r0 + ty + i * 4) * Cc + c0 + tx];
    __syncthreads();
    #pragma unroll
    for (int i = 0; i < 16; i++) {
        int cc = ty + i * 4;
        op[(long)(c0 + cc) * R + r0 + tx] = (bf16_t)t[tx][cc];
    }
}

// ------- fused QKV weight prep: 9 (set,part) sources in one launch -------
struct QkvSrc { const float* p[9]; };
__global__ __launch_bounds__(256) void tcvt_qkv_k(QkvSrc srcs, bf16_t* __restrict__ outp)
{
    int z = blockIdx.z;
    int si = z >> 5, zb = (z >> 3) & 3, zh = z & 7;
    int set = si / 3, part = si - set * 3;
    const float* in = srcs.p[si] + (long)zb * (Hn * Cdim * HDim) + (long)zh * (Cdim * HDim);
    bf16_t* op = outp + ((long)set * Ld + zb) * (1536L * Cdim)
                      + (long)part * 512 * Cdim + (long)zh * 64 * Cdim;
    __shared__ float t[64][65];
    int r0 = blockIdx.y * 64;
    int tx = threadIdx.x & 63, ty = threadIdx.x >> 6;
    #pragma unroll
    for (int i = 0; i < 16; i++)
        t[ty + i * 4][tx] = in[(long)(r0 + ty + i * 4) * HDim + tx];
    __syncthreads();
    #pragma unroll
    for (int i = 0; i < 16; i++) {
        int cc = ty + i * 4;
        op[(long)cc * Cdim + r0 + tx] = (bf16_t)t[tx][cc];
    }
}

// ================= bf16 MFMA GEMM: C = op(Asel @ Bt^T) =================
// A [M,K] bf16 row-major (lda), Bt [N,K] bf16 row-major (ldb). BK=32/64.
// 256 threads = 4 waves (2x2). LDS tiles use a chunk-XOR swizzle (rule #21:
// linear LDS dest for global_load_lds, pre-swizzled GLOBAL source + swizzled
// ds_read) -> fragment reads are bank-conflict-free.
// A-select: tiles with bn >= aSplit read A2. VOUT: cols >= vSplit scattered
// transposed into vt. XOUT: also write bf16 copy. SWZM>0: XCD-aware remap.
template<int BM, int BN, int BK, bool BIAS, bool RELU, bool RES, bool OBF,
         bool VOUT, int SWZM, bool XOUT>
__global__ __launch_bounds__(256) void mgemm_k(
    const bf16_t* __restrict__ A, const bf16_t* __restrict__ A2, int aSplit,
    const bf16_t* __restrict__ Bt, const float* __restrict__ bias,
    const float* __restrict__ res, void* __restrict__ Cout,
    bf16_t* __restrict__ xout, bf16_t* __restrict__ vtout, int vSplit,
    int K, int lda, int ldb, int ldc)
{
    constexpr int MR = BM / 32;
    constexpr int NR = BN / 32;
    constexpr int KK = BK / 32;
    constexpr int LPR = BK / 8;     // 16B chunks per LDS row (= lanes per row in staging)
    __shared__ bf16_t As[BM * BK];
    __shared__ bf16_t Bs[BN * BK];

    int tid = threadIdx.x;
    int wv = tid >> 6, lane = tid & 63;
    int bm, bn;
    if constexpr (SWZM > 0) {
        int lin = blockIdx.y * gridDim.x + blockIdx.x;
        int tot = gridDim.x * gridDim.y;
        int chunk = tot >> 3;
        int e = (lin & 7) * chunk + (lin >> 3);
        bm = (e % SWZM) * BM;
        bn = (e / SWZM) * BN;
    } else {
        bm = blockIdx.y * BM; bn = blockIdx.x * BN;
    }
    const bf16_t* Ab = (bn < aSplit) ? A : A2;
    int wr = wv >> 1, wc = wv & 1;

    f32x4 acc[MR][NR];
    #pragma unroll
    for (int i = 0; i < MR; i++)
        #pragma unroll
        for (int j = 0; j < NR; j++)
            acc[i][j] = (f32x4){0.f, 0.f, 0.f, 0.f};

    constexpr int RPW = 512 / BK;   // rows per wave-chunk in staging
    constexpr int RPP = 2048 / BK;  // rows per 256-thread pass
    const int sr  = lane / LPR;                              // staging row within chunk
    const int sc8 = ((lane % LPR) ^ (sr & (LPR - 1))) * 8;   // pre-swizzled source chunk
    const int r16 = lane & 15, g4 = lane >> 4;

    for (int k0 = 0; k0 < K; k0 += BK) {
        #pragma unroll
        for (int p = 0; p < BM * BK / 2048; p++) {
            int rb = p * RPP + wv * RPW;
            const bf16_t* g = Ab + (long)(bm + rb + sr) * lda + (k0 + sc8);
            __builtin_amdgcn_global_load_lds(
                (const __attribute__((address_space(1))) void*)g,
                (__attribute__((address_space(3))) void*)&As[rb * BK],
                16, 0, 0);
        }
        #pragma unroll
        for (int p = 0; p < BN * BK / 2048; p++) {
            int rb = p * RPP + wv * RPW;
            const bf16_t* g = Bt + (long)(bn + rb + sr) * ldb + (k0 + sc8);
            __builtin_amdgcn_global_load_lds(
                (const __attribute__((address_space(1))) void*)g,
                (__attribute__((address_space(3))) void*)&Bs[rb * BK],
                16, 0, 0);
        }
        __syncthreads();

        #pragma unroll
        for (int kk = 0; kk < KK; kk++) {
            bf16x8 bkk[NR];
            #pragma unroll
            for (int j = 0; j < NR; j++) {
                int row = wc * (BN / 2) + j * 16 + r16;
                bkk[j] = *(const bf16x8*)&Bs[row * BK + (((kk * 4 + g4) ^ (row & (LPR - 1))) * 8)];
            }
            #pragma unroll
            for (int i = 0; i < MR; i++) {
                int row = wr * (BM / 2) + i * 16 + r16;
                bf16x8 a = *(const bf16x8*)&As[row * BK + (((kk * 4 + g4) ^ (row & (LPR - 1))) * 8)];
                #pragma unroll
                for (int j = 0; j < NR; j++)
                    acc[i][j] = __builtin_amdgcn_mfma_f32_16x16x32_bf16(a, bkk[j], acc[i][j], 0, 0, 0);
            }
        }
        __syncthreads();
    }

    // ---- epilogue: C/D layout col=lane&15, row=(lane>>4)*4+q ----
    int crow0 = g4 * 4;
    int ccol  = r16;
    #pragma unroll
    for (int i = 0; i < MR; i++) {
        #pragma unroll
        for (int j = 0; j < NR; j++) {
            int gr = bm + wr * (BM / 2) + i * 16 + crow0;
            int gc = bn + wc * (BN / 2) + j * 16 + ccol;
            float bv = BIAS ? bias[gc] : 0.f;
            #pragma unroll
            for (int q = 0; q < 4; q++) {
                float v = acc[i][j][q];
                if (BIAS) v += bv;
                if (RELU) v = fmaxf(v, 0.f);
                if (VOUT && gc >= vSplit) {
                    int row = gr + q;
                    int b = row >> 10, t = row & (Tn - 1);
                    vtout[((long)b * 512 + (gc - vSplit)) * Tn + t] = (bf16_t)v;
                } else {
                    long oidx = (long)(gr + q) * ldc + gc;
                    if (RES)  v += res[oidx];
                    if (OBF) ((bf16_t*)Cout)[oidx] = (bf16_t)v;
                    else     ((float*) Cout)[oidx] = v;
                    if (XOUT) xout[oidx] = (bf16_t)v;
                }
            }
        }
    }
}

// ================= fused flash attention (8 waves, KV-split even/odd) =================
// grid (T/64, B*H), 512 threads. Waves 0-3 (group 0) take even KV tiles, 4-7 odd,
// over the SAME 64 q-rows; states merged at the end via LDS.
template<bool CAUSAL, bool HASMASK>
__global__ __launch_bounds__(512, 2) void flash_k(
    const bf16_t* __restrict__ qkv, const bf16_t* __restrict__ vt,
    const int* __restrict__ mask, bf16_t* __restrict__ ao)
{
    __shared__ bf16_t Kl[2][64][72];
    __shared__ bf16_t Vl[2][64][72];
    __shared__ bf16_t Pl[8][16][72];

    int qt = blockIdx.x, bh = blockIdx.y;
    int b = bh >> 3, h = bh & 7;
    int tid = threadIdx.x, wv = tid >> 6, lane = tid & 63;
    int wg = wv >> 2, wq4 = wv & 3;
    int r16 = lane & 15, g4 = lane >> 4;
    int gtid = tid & 255;

    const bf16_t* qb = qkv + ((long)(b * Tn + qt * 64 + wq4 * 16 + r16)) * 1536 + h * 64;
    bf16x8 aq0 = *(const bf16x8*)&qb[g4 * 8];
    bf16x8 aq1 = *(const bf16x8*)&qb[32 + g4 * 8];

    f32x4 acc[4];
    #pragma unroll
    for (int j = 0; j < 4; j++) acc[j] = (f32x4){0.f, 0.f, 0.f, 0.f};
    float m_[4], l_[4];
    #pragma unroll
    for (int q = 0; q < 4; q++) { m_[q] = -1e30f; l_[q] = 0.f; }

    int lastT = CAUSAL ? qt : (Tn / 64 - 1);
    int niter = CAUSAL ? (qt / 2 + 1) : (Tn / 128);
    int krow = gtid >> 3, kcol = (gtid & 7) * 8;   // 32 rows/pass, 2 passes

    for (int it = 0; it < niter; it++) {
        int t = 2 * it + wg;
        bool active = t <= lastT;
        int s0 = t * 64;
        bf16x8 kr[2], vr[2];
        int mv = 0;
        if (active) {
            #pragma unroll
            for (int i = 0; i < 2; i++)
                kr[i] = *(const bf16x8*)&qkv[((long)(b * Tn + s0 + krow + i * 32)) * 1536 + 512 + h * 64 + kcol];
            #pragma unroll
            for (int i = 0; i < 2; i++)
                vr[i] = *(const bf16x8*)&vt[((long)(bh * 64 + krow + i * 32)) * Tn + s0 + kcol];
            if (HASMASK) mv = mask[b * Tn + s0 + lane];
        }
        __syncthreads();                      // prior tile consumed
        if (active) {
            #pragma unroll
            for (int i = 0; i < 2; i++) *(bf16x8*)&Kl[wg][krow + i * 32][kcol] = kr[i];
            #pragma unroll
            for (int i = 0; i < 2; i++) *(bf16x8*)&Vl[wg][krow + i * 32][kcol] = vr[i];
        }
        __syncthreads();                      // tiles visible
        if (!active) continue;

        // ---- QK^T: 8 MFMA ----
        f32x4 scv[4];
        __builtin_amdgcn_s_setprio(1);
        #pragma unroll
        for (int j = 0; j < 4; j++) {
            scv[j] = (f32x4){0.f, 0.f, 0.f, 0.f};
            bf16x8 bk0 = *(const bf16x8*)&Kl[wg][j * 16 + r16][g4 * 8];
            bf16x8 bk1 = *(const bf16x8*)&Kl[wg][j * 16 + r16][32 + g4 * 8];
            scv[j] = __builtin_amdgcn_mfma_f32_16x16x32_bf16(aq0, bk0, scv[j], 0, 0, 0);
            scv[j] = __builtin_amdgcn_mfma_f32_16x16x32_bf16(aq1, bk1, scv[j], 0, 0, 0);
        }
        __builtin_amdgcn_s_setprio(0);

        // ---- scale + mask ----
        bool diag = CAUSAL && (t == qt);
        #pragma unroll
        for (int j = 0; j < 4; j++) {
            int col = j * 16 + r16;
            int mm = 1;
            if (HASMASK) mm = __shfl(mv, col, 64);
            #pragma unroll
            for (int q = 0; q < 4; q++) {
                float v = scv[j][q] * 0.125f;
                if (diag && col > wq4 * 16 + g4 * 4 + q) v = -1e30f;
                if (HASMASK && mm == 0) v = -1e30f;
                scv[j][q] = v;
            }
        }

        // ---- online softmax with defer-max (THR=8) ----
        float pmax[4];
        #pragma unroll
        for (int q = 0; q < 4; q++) {
            float v = fmaxf(fmaxf(scv[0][q], scv[1][q]), fmaxf(scv[2][q], scv[3][q]));
            v = fmaxf(v, __shfl_xor(v, 1, 64));
            v = fmaxf(v, __shfl_xor(v, 2, 64));
            v = fmaxf(v, __shfl_xor(v, 4, 64));
            v = fmaxf(v, __shfl_xor(v, 8, 64));
            pmax[q] = v;
        }
        bool skip = __all(pmax[0] <= m_[0] + 8.f && pmax[1] <= m_[1] + 8.f &&
                          pmax[2] <= m_[2] + 8.f && pmax[3] <= m_[3] + 8.f);
        if (!skip) {
            #pragma unroll
            for (int q = 0; q < 4; q++) {
                float mnew = fmaxf(m_[q], pmax[q]);
                float rf = __expf(m_[q] - mnew);
                l_[q] *= rf;
                #pragma unroll
                for (int j = 0; j < 4; j++) acc[j][q] *= rf;
                m_[q] = mnew;
            }
        }
        #pragma unroll
        for (int q = 0; q < 4; q++) {
            float rs = 0.f;
            #pragma unroll
            for (int j = 0; j < 4; j++) {
                float pv = __expf(scv[j][q] - m_[q]);
                scv[j][q] = pv;
                rs += pv;
            }
            rs += __shfl_xor(rs, 1, 64);
            rs += __shfl_xor(rs, 2, 64);
            rs += __shfl_xor(rs, 4, 64);
            rs += __shfl_xor(rs, 8, 64);
            l_[q] += rs;
        }

        // ---- P -> per-wave LDS (C/D layout -> A-frag layout) ----
        #pragma unroll
        for (int j = 0; j < 4; j++)
            #pragma unroll
            for (int q = 0; q < 4; q++)
                Pl[wv][g4 * 4 + q][j * 16 + r16] = (bf16_t)scv[j][q];
        asm volatile("s_waitcnt lgkmcnt(0)" ::: "memory");
        __builtin_amdgcn_sched_barrier(0);

        // ---- PV: 8 MFMA ----
        __builtin_amdgcn_s_setprio(1);
        #pragma unroll
        for (int c = 0; c < 2; c++) {
            bf16x8 pa = *(const bf16x8*)&Pl[wv][r16][c * 32 + g4 * 8];
            #pragma unroll
            for (int j = 0; j < 4; j++) {
                bf16x8 bv = *(const bf16x8*)&Vl[wg][j * 16 + r16][c * 32 + g4 * 8];
                acc[j] = __builtin_amdgcn_mfma_f32_16x16x32_bf16(pa, bv, acc[j], 0, 0, 0);
            }
        }
        __builtin_amdgcn_s_setprio(0);
    }

    // ---- merge group 1 state into group 0 via LDS, write output ----
    float* accS = (float*)&Kl[0][0][0];      // [64][64] f32 = 16 KB (fits in Kl)
    float* mlS  = accS + 64 * 64;            // [64][2]
    __syncthreads();
    if (wg == 1) {
        #pragma unroll
        for (int j = 0; j < 4; j++)
            #pragma unroll
            for (int q = 0; q < 4; q++)
                accS[(wq4 * 16 + g4 * 4 + q) * 64 + j * 16 + r16] = acc[j][q];
        if (r16 == 0)
            #pragma unroll
            for (int q = 0; q < 4; q++) {
                mlS[(wq4 * 16 + g4 * 4 + q) * 2 + 0] = m_[q];
                mlS[(wq4 * 16 + g4 * 4 + q) * 2 + 1] = l_[q];
            }
    }
    __syncthreads();
    if (wg == 0) {
        bf16_t* aob = ao + ((long)(b * Tn + qt * 64 + wq4 * 16 + g4 * 4)) * Cdim + h * 64;
        #pragma unroll
        for (int q = 0; q < 4; q++) {
            int row = wq4 * 16 + g4 * 4 + q;
            float mB = mlS[row * 2], lB = mlS[row * 2 + 1];
            float mS = fmaxf(m_[q], mB);
            float fA = __expf(m_[q] - mS), fB = __expf(mB - mS);
            float lS = l_[q] * fA + lB * fB;
            float inv = 1.f / lS;
            #pragma unroll
            for (int j = 0; j < 4; j++) {
                float o = (acc[j][q] * fA + accS[row * 64 + j * 16 + r16] * fB) * inv;
                aob[(long)q * Cdim + j * 16 + r16] = (bf16_t)o;
            }
        }
    }
}

// ================================ host orchestration ================================
static void run_attn(hipStream_t stream, const bf16_t* hq, const bf16_t* hkv,
    const bf16_t* wqkv, const float* bo, const bf16_t* wo_t,
    float* xres, const int* mask, bool causal,
    bf16_t* qkv, bf16_t* vt, bf16_t* ao)
{
    dim3 blk(256);
    // fused qkv projection: N=1536 (cols<512 read hq, else hkv); v-part -> vt
    mgemm_k<64,128,64,false,false,false,true,true,0,false><<<dim3(12, 32, 1), blk, 0, stream>>>(
        hq, hkv, 512, wqkv, nullptr, nullptr, qkv, nullptr, vt, 1024,
        Cdim, Cdim, Cdim, 1536);
    if (causal)
        flash_k<true,false><<<dim3(Tn / 64, Bn * Hn), dim3(512), 0, stream>>>(qkv, vt, nullptr, ao);
    else
        flash_k<false,true><<<dim3(Tn / 64, Bn * Hn), dim3(512), 0, stream>>>(qkv, vt, mask, ao);
    // out projection + bias + residual (f32, in place on xres)
    mgemm_k<64,64,64,true,false,true,false,false,0,false><<<dim3(8, 32, 1), blk, 0, stream>>>(
        ao, ao, 1 << 30, wo_t, bo, xres, xres, nullptr, nullptr, 1 << 30,
        Cdim, Cdim, Cdim, Cdim);
}

extern "C" void kernel_launch(void* const* d_in, const int* in_sizes, int n_in,
                              void* d_out, int out_size, void* d_ws, size_t ws_size,
                              hipStream_t stream)
{
    (void)in_sizes; (void)n_in; (void)out_size; (void)ws_size;
    const int*   enc_inp  = (const int*)d_in[0];
    const int*   dec_inp  = (const int*)d_in[1];
    const int*   enc_mask = (const int*)d_in[2];
    const float* tok_emb  = (const float*)d_in[3];
    const float* pos_emb  = (const float*)d_in[4];
    const float* e_wq  = (const float*)d_in[5];
    const float* e_wk  = (const float*)d_in[6];
    const float* e_wv  = (const float*)d_in[7];
    const float* e_wo  = (const float*)d_in[8];
    const float* e_bo  = (const float*)d_in[9];
    const float* dsa_wq = (const float*)d_in[10];
    const float* dsa_wk = (const float*)d_in[11];
    const float* dsa_wv = (const float*)d_in[12];
    const float* dsa_wo = (const float*)d_in[13];
    const float* dsa_bo = (const float*)d_in[14];
    const float* dca_wq = (const float*)d_in[15];
    const float* dca_wk = (const float*)d_in[16];
    const float* dca_wv = (const float*)d_in[17];
    const float* dca_wo = (const float*)d_in[18];
    const float* dca_bo = (const float*)d_in[19];
    const float* e_ln1_g = (const float*)d_in[20];
    const float* e_ln1_b = (const float*)d_in[21];
    const float* e_ln2_g = (const float*)d_in[22];
    const float* e_ln2_b = (const float*)d_in[23];
    const float* d_ln1_g = (const float*)d_in[24];
    const float* d_ln1_b = (const float*)d_in[25];
    const float* d_ln2_g = (const float*)d_in[26];
    const float* d_ln2_b = (const float*)d_in[27];
    const float* d_ln3_g = (const float*)d_in[28];
    const float* d_ln3_b = (const float*)d_in[29];
    const float* e_w1 = (const float*)d_in[30];
    const float* e_b1 = (const float*)d_in[31];
    const float* e_w2 = (const float*)d_in[32];
    const float* e_b2 = (const float*)d_in[33];
    const float* d_w1 = (const float*)d_in[34];
    const float* d_b1 = (const float*)d_in[35];
    const float* d_w2 = (const float*)d_in[36];
    const float* d_b2 = (const float*)d_in[37];
    const float* out_w = (const float*)d_in[38];
    const float* out_b = (const float*)d_in[39];
    float* out = (float*)d_out;

    // -------- workspace carve (bytes) --------
    char* p = (char*)d_ws;
    auto takeB = [&](size_t bytes) { char* r = p; p += (bytes + 255) & ~(size_t)255; return r; };
    float*  x_enc = (float*)takeB(1048576ull * 4);
    float*  x_dec = (float*)takeB(1048576ull * 4);
    bf16_t* h     = (bf16_t*)takeB(1048576ull * 2);
    bf16_t* hk    = (bf16_t*)takeB(1048576ull * 2);
    bf16_t* qkv   = (bf16_t*)takeB(3145728ull * 2);
    bf16_t* vt    = (bf16_t*)takeB(1048576ull * 2);
    bf16_t* ao    = (bf16_t*)takeB(1048576ull * 2);
    bf16_t* xdb   = (bf16_t*)takeB(1048576ull * 2);
    bf16_t* mid   = (bf16_t*)takeB(4194304ull * 2);
    bf16_t* wqkv_t = (bf16_t*)takeB(12ull * 786432 * 2);
    bf16_t* wo_t   = (bf16_t*)takeB(12ull * 262144 * 2);
    bf16_t* w1_t   = (bf16_t*)takeB(8ull * 1048576 * 2);
    bf16_t* w2_t   = (bf16_t*)takeB(8ull * 1048576 * 2);
    bf16_t* outw_t = (bf16_t*)takeB(16384000ull * 2);

    dim3 blk(256);
    const long LQKV = 1536L * Cdim;             // per-layer fused transposed qkv weights

    // ================= weight prep (5 launches) =================
    QkvSrc qs;
    qs.p[0] = e_wq;   qs.p[1] = e_wk;   qs.p[2] = e_wv;
    qs.p[3] = dsa_wq; qs.p[4] = dsa_wk; qs.p[5] = dsa_wv;
    qs.p[6] = dca_wq; qs.p[7] = dca_wk; qs.p[8] = dca_wv;
    tcvt_qkv_k<<<dim3(1, 8, 288), blk, 0, stream>>>(qs, wqkv_t);
    Ptr3 pw;
    pw.p[0] = e_wo; pw.p[1] = dsa_wo; pw.p[2] = dca_wo;
    tcvt_b_k<<<dim3(8, 8, 12), blk, 0, stream>>>(pw, wo_t, Cdim, Cdim, 4, (long)Cdim * Cdim);
    pw.p[0] = e_w1; pw.p[1] = d_w1; pw.p[2] = nullptr;
    tcvt_b_k<<<dim3(32, 8, 8), blk, 0, stream>>>(pw, w1_t, Cdim, FF, 4, (long)Cdim * FF);
    pw.p[0] = e_w2; pw.p[1] = d_w2; pw.p[2] = nullptr;
    tcvt_b_k<<<dim3(8, 32, 8), blk, 0, stream>>>(pw, w2_t, FF, Cdim, 4, (long)FF * Cdim);
    pw.p[0] = out_w; pw.p[1] = nullptr; pw.p[2] = nullptr;
    tcvt_b_k<<<dim3(500, 8, 1), blk, 0, stream>>>(pw, outw_t, Cdim, Vn, 1, 0);

    // ================= encoder =================
    embed_ln_k<<<NTOK, blk, 0, stream>>>(enc_inp, tok_emb, pos_emb, e_ln1_g, e_ln1_b, x_enc, h);
    for (int l = 0; l < Ld; l++) {
        if (l) ln_k<<<NTOK, blk, 0, stream>>>(x_enc, e_ln1_g + l * Cdim, e_ln1_b + l * Cdim, h);
        run_attn(stream, h, h,
                 wqkv_t + (long)l * LQKV, e_bo + l * Cdim, wo_t + (long)l * Cdim * Cdim,
                 x_enc, enc_mask, /*causal=*/false, qkv, vt, ao);
        ln_k<<<NTOK, blk, 0, stream>>>(x_enc, e_ln2_g + l * Cdim, e_ln2_b + l * Cdim, h);
        mgemm_k<128,128,64,true,true,false,true,false,0,false><<<dim3(16, 16, 1), blk, 0, stream>>>(
            h, h, 1 << 30, w1_t + (long)l * Cdim * FF, e_b1 + l * FF, nullptr, mid,
            nullptr, nullptr, 1 << 30, Cdim, Cdim, Cdim, FF);
        mgemm_k<64,64,64,true,false,true,false,false,0,false><<<dim3(8, 32, 1), blk, 0, stream>>>(
            mid, mid, 1 << 30, w2_t + (long)l * FF * Cdim, e_b2 + l * Cdim, x_enc, x_enc,
            nullptr, nullptr, 1 << 30, FF, FF, FF, Cdim);
    }
    // x_enc now holds enc_out

    // ================= decoder =================
    embed_ln_k<<<NTOK, blk, 0, stream>>>(dec_inp, tok_emb, pos_emb, d_ln1_g, d_ln1_b, x_dec, h);
    for (int l = 0; l < Ld; l++) {
        // causal self-attention
        if (l) ln_k<<<NTOK, blk, 0, stream>>>(x_dec, d_ln1_g + l * Cdim, d_ln1_b + l * Cdim, h);
        run_attn(stream, h, h,
                 wqkv_t + (long)(Ld + l) * LQKV, dsa_bo + l * Cdim,
                 wo_t + (long)(Ld + l) * Cdim * Cdim,
                 x_dec, nullptr, /*causal=*/true, qkv, vt, ao);
        // cross-attention (same LN applied to x and enc_out) — one fused launch
        ln2_k<<<2 * NTOK, blk, 0, stream>>>(x_dec, x_enc,
            d_ln2_g + l * Cdim, d_ln2_b + l * Cdim, h, hk);
        run_attn(stream, h, hk,
                 wqkv_t + (long)(2 * Ld + l) * LQKV, dca_bo + l * Cdim,
                 wo_t + (long)(2 * Ld + l) * Cdim * Cdim,
                 x_dec, enc_mask, /*causal=*/false, qkv, vt, ao);
        // FFN
        ln_k<<<NTOK, blk, 0, stream>>>(x_dec, d_ln3_g + l * Cdim, d_ln3_b + l * Cdim, h);
        mgemm_k<128,128,64,true,true,false,true,false,0,false><<<dim3(16, 16, 1), blk, 0, stream>>>(
            h, h, 1 << 30, w1_t + (long)(Ld + l) * Cdim * FF, d_b1 + l * FF, nullptr, mid,
            nullptr, nullptr, 1 << 30, Cdim, Cdim, Cdim, FF);
        if (l < Ld - 1)
            mgemm_k<64,64,64,true,false,true,false,false,0,false><<<dim3(8, 32, 1), blk, 0, stream>>>(
                mid, mid, 1 << 30, w2_t + (long)(Ld + l) * FF * Cdim, d_b2 + l * Cdim, x_dec, x_dec,
                nullptr, nullptr, 1 << 30, FF, FF, FF, Cdim);
        else  // last layer: also emit bf16 copy for logits GEMM
            mgemm_k<64,64,64,true,false,true,false,false,0,true><<<dim3(8, 32, 1), blk, 0, stream>>>(
                mid, mid, 1 << 30, w2_t + (long)(Ld + l) * FF * Cdim, d_b2 + l * Cdim, x_dec, x_dec,
                xdb, nullptr, 1 << 30, FF, FF, FF, Cdim);
    }

    // ================= final logits (f32 out, 256x128 tile, XCD-swizzled) =================
    mgemm_k<256,128,64,true,false,false,false,false,8,false><<<dim3(250, 8, 1), blk, 0, stream>>>(
        xdb, xdb, 1 << 30, outw_t, out_b, nullptr, out, nullptr, nullptr, 1 << 30,
        Cdim, Cdim, Cdim, Vn);
}

// Round 7
// 1119.169 us; speedup vs baseline: 1.2126x; 1.0365x over previous
//
#include <hip/hip_runtime.h>
#include <hip/hip_bf16.h>
#include <math.h>

#define Cdim 512
#define Hn   8
#define HDim 64
#define Ld   4
#define Tn   1024
#define Bn   2
#define NTOK 2048   // B*T
#define FF   2048   // 4*C
#define Vn   32000

typedef __bf16 bf16_t;
typedef __bf16 bf16x8 __attribute__((ext_vector_type(8)));
typedef __bf16 bf16x4 __attribute__((ext_vector_type(4)));
typedef float  f32x4  __attribute__((ext_vector_type(4)));

// ---------------- layernorm: one wave per row, 4 rows/block, no barriers ----------------
__device__ __forceinline__ void ln_wave(const float* __restrict__ xr,
    const float* __restrict__ g, const float* __restrict__ bb,
    bf16_t* __restrict__ yr, int lane)
{
    f32x4 a = *(const f32x4*)&xr[lane * 8];
    f32x4 c = *(const f32x4*)&xr[lane * 8 + 4];
    float s = a[0] + a[1] + a[2] + a[3] + c[0] + c[1] + c[2] + c[3];
    #pragma unroll
    for (int o = 1; o < 64; o <<= 1) s += __shfl_xor(s, o, 64);
    float mean = s * (1.f / Cdim);
    float d[8], qv = 0.f;
    #pragma unroll
    for (int k = 0; k < 4; k++) { d[k] = a[k] - mean; d[4 + k] = c[k] - mean; }
    #pragma unroll
    for (int k = 0; k < 8; k++) qv += d[k] * d[k];
    #pragma unroll
    for (int o = 1; o < 64; o <<= 1) qv += __shfl_xor(qv, o, 64);
    float inv = rsqrtf(qv * (1.f / Cdim) + 1e-5f);
    f32x4 g0 = *(const f32x4*)&g[lane * 8],  g1 = *(const f32x4*)&g[lane * 8 + 4];
    f32x4 b0 = *(const f32x4*)&bb[lane * 8], b1 = *(const f32x4*)&bb[lane * 8 + 4];
    bf16x8 o;
    #pragma unroll
    for (int k = 0; k < 4; k++) {
        o[k]     = (bf16_t)(d[k]     * inv * g0[k] + b0[k]);
        o[4 + k] = (bf16_t)(d[4 + k] * inv * g1[k] + b1[k]);
    }
    *(bf16x8*)&yr[lane * 8] = o;
}

__global__ __launch_bounds__(256) void ln_k(const float* __restrict__ x,
    const float* __restrict__ g, const float* __restrict__ bb, bf16_t* __restrict__ y)
{
    int wid = threadIdx.x >> 6, lane = threadIdx.x & 63;
    int row = blockIdx.x * 4 + wid;
    ln_wave(x + (long)row * Cdim, g, bb, y + (long)row * Cdim, lane);
}

// two-source LN (cross-attention): rows < NTOK from x1->y1, else x2->y2 (same g,b)
__global__ __launch_bounds__(256) void ln2_k(const float* __restrict__ x1,
    const float* __restrict__ x2, const float* __restrict__ g,
    const float* __restrict__ bb, bf16_t* __restrict__ y1, bf16_t* __restrict__ y2)
{
    int wid = threadIdx.x >> 6, lane = threadIdx.x & 63;
    int row = blockIdx.x * 4 + wid;
    const float* x = (row < NTOK) ? x1 : x2;
    bf16_t*      y = (row < NTOK) ? y1 : y2;
    int r = row & (NTOK - 1);
    ln_wave(x + (long)r * Cdim, g, bb, y + (long)r * Cdim, lane);
}

// ---------------- fused embedding + first-layer LN (wave per row) ----------------
__global__ __launch_bounds__(256) void embed_ln_k(const int* __restrict__ inp,
    const float* __restrict__ tok, const float* __restrict__ pos,
    const float* __restrict__ g, const float* __restrict__ bb,
    float* __restrict__ x, bf16_t* __restrict__ y)
{
    int wid = threadIdx.x >> 6, lane = threadIdx.x & 63;
    int bt = blockIdx.x * 4 + wid;
    int t = bt & (Tn - 1);
    long toff = (long)inp[bt] * Cdim;
    f32x4 a = *(const f32x4*)&tok[toff + lane * 8];
    f32x4 c = *(const f32x4*)&tok[toff + lane * 8 + 4];
    f32x4 pa = *(const f32x4*)&pos[(long)t * Cdim + lane * 8];
    f32x4 pc = *(const f32x4*)&pos[(long)t * Cdim + lane * 8 + 4];
    a += pa; c += pc;
    float* xr = x + (long)bt * Cdim;
    *(f32x4*)&xr[lane * 8] = a;
    *(f32x4*)&xr[lane * 8 + 4] = c;
    // inline LN on registers
    float s = a[0] + a[1] + a[2] + a[3] + c[0] + c[1] + c[2] + c[3];
    #pragma unroll
    for (int o = 1; o < 64; o <<= 1) s += __shfl_xor(s, o, 64);
    float mean = s * (1.f / Cdim);
    float d[8], qv = 0.f;
    #pragma unroll
    for (int k = 0; k < 4; k++) { d[k] = a[k] - mean; d[4 + k] = c[k] - mean; }
    #pragma unroll
    for (int k = 0; k < 8; k++) qv += d[k] * d[k];
    #pragma unroll
    for (int o = 1; o < 64; o <<= 1) qv += __shfl_xor(qv, o, 64);
    float inv = rsqrtf(qv * (1.f / Cdim) + 1e-5f);
    f32x4 g0 = *(const f32x4*)&g[lane * 8],  g1 = *(const f32x4*)&g[lane * 8 + 4];
    f32x4 b0 = *(const f32x4*)&bb[lane * 8], b1 = *(const f32x4*)&bb[lane * 8 + 4];
    bf16x8 o;
    #pragma unroll
    for (int k = 0; k < 4; k++) {
        o[k]     = (bf16_t)(d[k]     * inv * g0[k] + b0[k]);
        o[4 + k] = (bf16_t)(d[4 + k] * inv * g1[k] + b1[k]);
    }
    *(bf16x8*)&y[(long)bt * Cdim + lane * 8] = o;
}

// ------- batched tiled transpose+convert: f32 [R,Cc] -> bf16 [Cc,R] over z sources/layers -------
struct Ptr3 { const float* p[3]; };
__global__ __launch_bounds__(256) void tcvt_b_k(Ptr3 srcs, bf16_t* __restrict__ dst,
    int R, int Cc, int lps, long dstStride)
{
    int z = blockIdx.z; int s = z / lps, l = z - s * lps;
    const float* in = srcs.p[s] + (long)l * R * Cc;
    bf16_t* op = dst + (long)z * dstStride;
    __shared__ float t[64][65];
    int r0 = blockIdx.y * 64, c0 = blockIdx.x * 64;
    int tx = threadIdx.x & 63, ty = threadIdx.x >> 6;
    #pragma unroll
    for (int i = 0; i < 16; i++)
        t[ty + i * 4][tx] = in[(long)(r0 + ty + i * 4) * Cc + c0 + tx];
    __syncthreads();
    #pragma unroll
    for (int i = 0; i < 16; i++) {
        int cc = ty + i * 4;
        op[(long)(c0 + cc) * R + r0 + tx] = (bf16_t)t[tx][cc];
    }
}

// ------- fused QKV weight prep: 9 (set,part) sources in one launch -------
struct QkvSrc { const float* p[9]; };
__global__ __launch_bounds__(256) void tcvt_qkv_k(QkvSrc srcs, bf16_t* __restrict__ outp)
{
    int z = blockIdx.z;
    int si = z >> 5, zb = (z >> 3) & 3, zh = z & 7;
    int set = si / 3, part = si - set * 3;
    const float* in = srcs.p[si] + (long)zb * (Hn * Cdim * HDim) + (long)zh * (Cdim * HDim);
    bf16_t* op = outp + ((long)set * Ld + zb) * (1536L * Cdim)
                      + (long)part * 512 * Cdim + (long)zh * 64 * Cdim;
    __shared__ float t[64][65];
    int r0 = blockIdx.y * 64;
    int tx = threadIdx.x & 63, ty = threadIdx.x >> 6;
    #pragma unroll
    for (int i = 0; i < 16; i++)
        t[ty + i * 4][tx] = in[(long)(r0 + ty + i * 4) * HDim + tx];
    __syncthreads();
    #pragma unroll
    for (int i = 0; i < 16; i++) {
        int cc = ty + i * 4;
        op[(long)cc * Cdim + r0 + tx] = (bf16_t)t[tx][cc];
    }
}

// ================= bf16 MFMA GEMM: C = op(Asel @ Bt^T) =================
// 256 threads = 4 waves (2x2). Chunk-XOR LDS swizzle (conflict-free staging reads).
// COAL: epilogue bounces acc through per-wave padded LDS -> coalesced f32x4 /
// bf16x8 stores (and f32x4 residual reads). VOUT kernels keep scalar epilogue.
template<int BM, int BN, int BK, bool BIAS, bool RELU, bool RES, bool OBF,
         bool VOUT, int SWZM, bool XOUT, bool COAL>
__global__ __launch_bounds__(256) void mgemm_k(
    const bf16_t* __restrict__ A, const bf16_t* __restrict__ A2, int aSplit,
    const bf16_t* __restrict__ Bt, const float* __restrict__ bias,
    const float* __restrict__ res, void* __restrict__ Cout,
    bf16_t* __restrict__ xout, bf16_t* __restrict__ vtout, int vSplit,
    int K, int lda, int ldb, int ldc)
{
    constexpr int MR = BM / 32;
    constexpr int NR = BN / 32;
    constexpr int KK = BK / 32;
    constexpr int LPR = BK / 8;
    __shared__ bf16_t As[BM * BK];
    __shared__ bf16_t Bs[BN * BK];
    __shared__ float cws[COAL ? 4 * 16 * 36 : 1];

    int tid = threadIdx.x;
    int wv = tid >> 6, lane = tid & 63;
    int bm, bn;
    if constexpr (SWZM > 0) {
        int lin = blockIdx.y * gridDim.x + blockIdx.x;
        int tot = gridDim.x * gridDim.y;
        int chunk = tot >> 3;
        int e = (lin & 7) * chunk + (lin >> 3);
        bm = (e % SWZM) * BM;
        bn = (e / SWZM) * BN;
    } else {
        bm = blockIdx.y * BM; bn = blockIdx.x * BN;
    }
    const bf16_t* Ab = (bn < aSplit) ? A : A2;
    int wr = wv >> 1, wc = wv & 1;

    f32x4 acc[MR][NR];
    #pragma unroll
    for (int i = 0; i < MR; i++)
        #pragma unroll
        for (int j = 0; j < NR; j++)
            acc[i][j] = (f32x4){0.f, 0.f, 0.f, 0.f};

    constexpr int RPW = 512 / BK;
    constexpr int RPP = 2048 / BK;
    const int sr  = lane / LPR;
    const int sc8 = ((lane % LPR) ^ (sr & (LPR - 1))) * 8;
    const int r16 = lane & 15, g4 = lane >> 4;

    for (int k0 = 0; k0 < K; k0 += BK) {
        #pragma unroll
        for (int p = 0; p < BM * BK / 2048; p++) {
            int rb = p * RPP + wv * RPW;
            const bf16_t* g = Ab + (long)(bm + rb + sr) * lda + (k0 + sc8);
            __builtin_amdgcn_global_load_lds(
                (const __attribute__((address_space(1))) void*)g,
                (__attribute__((address_space(3))) void*)&As[rb * BK],
                16, 0, 0);
        }
        #pragma unroll
        for (int p = 0; p < BN * BK / 2048; p++) {
            int rb = p * RPP + wv * RPW;
            const bf16_t* g = Bt + (long)(bn + rb + sr) * ldb + (k0 + sc8);
            __builtin_amdgcn_global_load_lds(
                (const __attribute__((address_space(1))) void*)g,
                (__attribute__((address_space(3))) void*)&Bs[rb * BK],
                16, 0, 0);
        }
        __syncthreads();

        #pragma unroll
        for (int kk = 0; kk < KK; kk++) {
            bf16x8 bkk[NR];
            #pragma unroll
            for (int j = 0; j < NR; j++) {
                int row = wc * (BN / 2) + j * 16 + r16;
                bkk[j] = *(const bf16x8*)&Bs[row * BK + (((kk * 4 + g4) ^ (row & (LPR - 1))) * 8)];
            }
            #pragma unroll
            for (int i = 0; i < MR; i++) {
                int row = wr * (BM / 2) + i * 16 + r16;
                bf16x8 a = *(const bf16x8*)&As[row * BK + (((kk * 4 + g4) ^ (row & (LPR - 1))) * 8)];
                #pragma unroll
                for (int j = 0; j < NR; j++)
                    acc[i][j] = __builtin_amdgcn_mfma_f32_16x16x32_bf16(a, bkk[j], acc[i][j], 0, 0, 0);
            }
        }
        __syncthreads();
    }

    if constexpr (COAL) {
        // ---- coalesced epilogue via per-wave LDS bounce (no barriers needed) ----
        #pragma unroll
        for (int i = 0; i < MR; i++) {
            int gr0 = bm + wr * (BM / 2) + i * 16;
            #pragma unroll
            for (int hh = 0; hh < NR / 2; hh++) {
                #pragma unroll
                for (int jj = 0; jj < 2; jj++) {
                    int j = hh * 2 + jj;
                    int gc = bn + wc * (BN / 2) + j * 16 + r16;
                    float bv = BIAS ? bias[gc] : 0.f;
                    #pragma unroll
                    for (int q = 0; q < 4; q++) {
                        float v = acc[i][j][q];
                        if (BIAS) v += bv;
                        if (RELU) v = fmaxf(v, 0.f);
                        cws[(wv * 16 + g4 * 4 + q) * 36 + jj * 16 + r16] = v;
                    }
                }
                int gcb = bn + wc * (BN / 2) + hh * 32;
                if constexpr (OBF) {
                    int row = lane >> 2, c8 = (lane & 3) * 8;
                    f32x4 v0 = *(f32x4*)&cws[(wv * 16 + row) * 36 + c8];
                    f32x4 v1 = *(f32x4*)&cws[(wv * 16 + row) * 36 + c8 + 4];
                    long oidx = (long)(gr0 + row) * ldc + gcb + c8;
                    bf16x8 o;
                    #pragma unroll
                    for (int k = 0; k < 4; k++) { o[k] = (bf16_t)v0[k]; o[4 + k] = (bf16_t)v1[k]; }
                    *(bf16x8*)&((bf16_t*)Cout)[oidx] = o;
                } else {
                    #pragma unroll
                    for (int ps = 0; ps < 2; ps++) {
                        int row = (lane >> 3) + 8 * ps, c4 = (lane & 7) * 4;
                        f32x4 v = *(f32x4*)&cws[(wv * 16 + row) * 36 + c4];
                        long oidx = (long)(gr0 + row) * ldc + gcb + c4;
                        if (RES) v += *(const f32x4*)&res[oidx];
                        *(f32x4*)&((float*)Cout)[oidx] = v;
                        if (XOUT) {
                            bf16x4 o;
                            #pragma unroll
                            for (int k = 0; k < 4; k++) o[k] = (bf16_t)v[k];
                            *(bf16x4*)&xout[oidx] = o;
                        }
                    }
                }
            }
        }
    } else {
        // ---- scalar epilogue (VOUT scatter path) ----
        #pragma unroll
        for (int i = 0; i < MR; i++) {
            #pragma unroll
            for (int j = 0; j < NR; j++) {
                int gr = bm + wr * (BM / 2) + i * 16 + g4 * 4;
                int gc = bn + wc * (BN / 2) + j * 16 + r16;
                float bv = BIAS ? bias[gc] : 0.f;
                #pragma unroll
                for (int q = 0; q < 4; q++) {
                    float v = acc[i][j][q];
                    if (BIAS) v += bv;
                    if (RELU) v = fmaxf(v, 0.f);
                    if (VOUT && gc >= vSplit) {
                        int row = gr + q;
                        int b = row >> 10, t = row & (Tn - 1);
                        vtout[((long)b * 512 + (gc - vSplit)) * Tn + t] = (bf16_t)v;
                    } else {
                        long oidx = (long)(gr + q) * ldc + gc;
                        if (RES)  v += res[oidx];
                        if (OBF) ((bf16_t*)Cout)[oidx] = (bf16_t)v;
                        else     ((float*) Cout)[oidx] = v;
                        if (XOUT) xout[oidx] = (bf16_t)v;
                    }
                }
            }
        }
    }
}

// ================= fused flash attention (8 waves, KV-split even/odd, T14 prefetch) ==========
template<bool CAUSAL, bool HASMASK>
__global__ __launch_bounds__(512, 2) void flash_k(
    const bf16_t* __restrict__ qkv, const bf16_t* __restrict__ vt,
    const int* __restrict__ mask, bf16_t* __restrict__ ao)
{
    __shared__ bf16_t Kl[2][64][72];
    __shared__ bf16_t Vl[2][64][72];
    __shared__ bf16_t Pl[8][16][72];

    int qt = blockIdx.x, bh = blockIdx.y;
    int b = bh >> 3, h = bh & 7;
    int tid = threadIdx.x, wv = tid >> 6, lane = tid & 63;
    int wg = wv >> 2, wq4 = wv & 3;
    int r16 = lane & 15, g4 = lane >> 4;
    int gtid = tid & 255;

    const bf16_t* qb = qkv + ((long)(b * Tn + qt * 64 + wq4 * 16 + r16)) * 1536 + h * 64;
    bf16x8 aq0 = *(const bf16x8*)&qb[g4 * 8];
    bf16x8 aq1 = *(const bf16x8*)&qb[32 + g4 * 8];

    f32x4 acc[4];
    #pragma unroll
    for (int j = 0; j < 4; j++) acc[j] = (f32x4){0.f, 0.f, 0.f, 0.f};
    float m_[4], l_[4];
    #pragma unroll
    for (int q = 0; q < 4; q++) { m_[q] = -1e30f; l_[q] = 0.f; }

    int lastT = CAUSAL ? qt : (Tn / 64 - 1);
    int niter = CAUSAL ? (qt / 2 + 1) : (Tn / 128);
    int krow = gtid >> 3, kcol = (gtid & 7) * 8;   // 32 rows/pass, 2 passes

    // prologue prefetch (it = 0)
    bf16x8 kr[2], vr[2];
    int mv = 0;
    {
        int t0 = wg;
        if (t0 <= lastT) {
            int s0 = t0 * 64;
            #pragma unroll
            for (int i = 0; i < 2; i++)
                kr[i] = *(const bf16x8*)&qkv[((long)(b * Tn + s0 + krow + i * 32)) * 1536 + 512 + h * 64 + kcol];
            #pragma unroll
            for (int i = 0; i < 2; i++)
                vr[i] = *(const bf16x8*)&vt[((long)(bh * 64 + krow + i * 32)) * Tn + s0 + kcol];
            if (HASMASK) mv = mask[b * Tn + s0 + lane];
        }
    }

    for (int it = 0; it < niter; it++) {
        int t = 2 * it + wg;
        bool active = t <= lastT;
        __syncthreads();                      // prior tile consumed
        if (active) {
            #pragma unroll
            for (int i = 0; i < 2; i++) *(bf16x8*)&Kl[wg][krow + i * 32][kcol] = kr[i];
            #pragma unroll
            for (int i = 0; i < 2; i++) *(bf16x8*)&Vl[wg][krow + i * 32][kcol] = vr[i];
        }
        __syncthreads();                      // tiles visible
        int mv_use = mv;
        // ---- prefetch next tile (hides HBM/L2 latency under compute) ----
        int tn = t + 2;
        if (it + 1 < niter && tn <= lastT) {
            int sn = tn * 64;
            #pragma unroll
            for (int i = 0; i < 2; i++)
                kr[i] = *(const bf16x8*)&qkv[((long)(b * Tn + sn + krow + i * 32)) * 1536 + 512 + h * 64 + kcol];
            #pragma unroll
            for (int i = 0; i < 2; i++)
                vr[i] = *(const bf16x8*)&vt[((long)(bh * 64 + krow + i * 32)) * Tn + sn + kcol];
            if (HASMASK) mv = mask[b * Tn + sn + lane];
        }
        if (!active) continue;

        // ---- QK^T: 8 MFMA ----
        f32x4 scv[4];
        __builtin_amdgcn_s_setprio(1);
        #pragma unroll
        for (int j = 0; j < 4; j++) {
            scv[j] = (f32x4){0.f, 0.f, 0.f, 0.f};
            bf16x8 bk0 = *(const bf16x8*)&Kl[wg][j * 16 + r16][g4 * 8];
            bf16x8 bk1 = *(const bf16x8*)&Kl[wg][j * 16 + r16][32 + g4 * 8];
            scv[j] = __builtin_amdgcn_mfma_f32_16x16x32_bf16(aq0, bk0, scv[j], 0, 0, 0);
            scv[j] = __builtin_amdgcn_mfma_f32_16x16x32_bf16(aq1, bk1, scv[j], 0, 0, 0);
        }
        __builtin_amdgcn_s_setprio(0);

        // ---- scale + mask ----
        bool diag = CAUSAL && (t == qt);
        #pragma unroll
        for (int j = 0; j < 4; j++) {
            int col = j * 16 + r16;
            int mm = 1;
            if (HASMASK) mm = __shfl(mv_use, col, 64);
            #pragma unroll
            for (int q = 0; q < 4; q++) {
                float v = scv[j][q] * 0.125f;
                if (diag && col > wq4 * 16 + g4 * 4 + q) v = -1e30f;
                if (HASMASK && mm == 0) v = -1e30f;
                scv[j][q] = v;
            }
        }

        // ---- online softmax with defer-max (THR=8) ----
        float pmax[4];
        #pragma unroll
        for (int q = 0; q < 4; q++) {
            float v = fmaxf(fmaxf(scv[0][q], scv[1][q]), fmaxf(scv[2][q], scv[3][q]));
            v = fmaxf(v, __shfl_xor(v, 1, 64));
            v = fmaxf(v, __shfl_xor(v, 2, 64));
            v = fmaxf(v, __shfl_xor(v, 4, 64));
            v = fmaxf(v, __shfl_xor(v, 8, 64));
            pmax[q] = v;
        }
        bool skip = __all(pmax[0] <= m_[0] + 8.f && pmax[1] <= m_[1] + 8.f &&
                          pmax[2] <= m_[2] + 8.f && pmax[3] <= m_[3] + 8.f);
        if (!skip) {
            #pragma unroll
            for (int q = 0; q < 4; q++) {
                float mnew = fmaxf(m_[q], pmax[q]);
                float rf = __expf(m_[q] - mnew);
                l_[q] *= rf;
                #pragma unroll
                for (int j = 0; j < 4; j++) acc[j][q] *= rf;
                m_[q] = mnew;
            }
        }
        #pragma unroll
        for (int q = 0; q < 4; q++) {
            float rs = 0.f;
            #pragma unroll
            for (int j = 0; j < 4; j++) {
                float pv = __expf(scv[j][q] - m_[q]);
                scv[j][q] = pv;
                rs += pv;
            }
            rs += __shfl_xor(rs, 1, 64);
            rs += __shfl_xor(rs, 2, 64);
            rs += __shfl_xor(rs, 4, 64);
            rs += __shfl_xor(rs, 8, 64);
            l_[q] += rs;
        }

        // ---- P -> per-wave LDS (C/D layout -> A-frag layout) ----
        #pragma unroll
        for (int j = 0; j < 4; j++)
            #pragma unroll
            for (int q = 0; q < 4; q++)
                Pl[wv][g4 * 4 + q][j * 16 + r16] = (bf16_t)scv[j][q];
        asm volatile("s_waitcnt lgkmcnt(0)" ::: "memory");
        __builtin_amdgcn_sched_barrier(0);

        // ---- PV: 8 MFMA ----
        __builtin_amdgcn_s_setprio(1);
        #pragma unroll
        for (int c = 0; c < 2; c++) {
            bf16x8 pa = *(const bf16x8*)&Pl[wv][r16][c * 32 + g4 * 8];
            #pragma unroll
            for (int j = 0; j < 4; j++) {
                bf16x8 bv = *(const bf16x8*)&Vl[wg][j * 16 + r16][c * 32 + g4 * 8];
                acc[j] = __builtin_amdgcn_mfma_f32_16x16x32_bf16(pa, bv, acc[j], 0, 0, 0);
            }
        }
        __builtin_amdgcn_s_setprio(0);
    }

    // ---- merge group 1 state into group 0 via LDS, write output ----
    float* accS = (float*)&Kl[0][0][0];
    float* mlS  = accS + 64 * 64;
    __syncthreads();
    if (wg == 1) {
        #pragma unroll
        for (int j = 0; j < 4; j++)
            #pragma unroll
            for (int q = 0; q < 4; q++)
                accS[(wq4 * 16 + g4 * 4 + q) * 64 + j * 16 + r16] = acc[j][q];
        if (r16 == 0)
            #pragma unroll
            for (int q = 0; q < 4; q++) {
                mlS[(wq4 * 16 + g4 * 4 + q) * 2 + 0] = m_[q];
                mlS[(wq4 * 16 + g4 * 4 + q) * 2 + 1] = l_[q];
            }
    }
    __syncthreads();
    if (wg == 0) {
        bf16_t* aob = ao + ((long)(b * Tn + qt * 64 + wq4 * 16 + g4 * 4)) * Cdim + h * 64;
        #pragma unroll
        for (int q = 0; q < 4; q++) {
            int row = wq4 * 16 + g4 * 4 + q;
            float mB = mlS[row * 2], lB = mlS[row * 2 + 1];
            float mS = fmaxf(m_[q], mB);
            float fA = __expf(m_[q] - mS), fB = __expf(mB - mS);
            float lS = l_[q] * fA + lB * fB;
            float inv = 1.f / lS;
            #pragma unroll
            for (int j = 0; j < 4; j++) {
                float o = (acc[j][q] * fA + accS[row * 64 + j * 16 + r16] * fB) * inv;
                aob[(long)q * Cdim + j * 16 + r16] = (bf16_t)o;
            }
        }
    }
}

// ================================ host orchestration ================================
static void run_attn(hipStream_t stream, const bf16_t* hq, const bf16_t* hkv,
    const bf16_t* wqkv, const float* bo, const bf16_t* wo_t,
    float* xres, const int* mask, bool causal,
    bf16_t* qkv, bf16_t* vt, bf16_t* ao)
{
    dim3 blk(256);
    // fused qkv projection: N=1536 (cols<512 read hq, else hkv); v-part -> vt
    mgemm_k<64,128,64,false,false,false,true,true,0,false,false><<<dim3(12, 32, 1), blk, 0, stream>>>(
        hq, hkv, 512, wqkv, nullptr, nullptr, qkv, nullptr, vt, 1024,
        Cdim, Cdim, Cdim, 1536);
    if (causal)
        flash_k<true,false><<<dim3(Tn / 64, Bn * Hn), dim3(512), 0, stream>>>(qkv, vt, nullptr, ao);
    else
        flash_k<false,true><<<dim3(Tn / 64, Bn * Hn), dim3(512), 0, stream>>>(qkv, vt, mask, ao);
    // out projection + bias + residual (f32, in place on xres) — coalesced epilogue
    mgemm_k<64,64,64,true,false,true,false,false,0,false,true><<<dim3(8, 32, 1), blk, 0, stream>>>(
        ao, ao, 1 << 30, wo_t, bo, xres, xres, nullptr, nullptr, 1 << 30,
        Cdim, Cdim, Cdim, Cdim);
}

extern "C" void kernel_launch(void* const* d_in, const int* in_sizes, int n_in,
                              void* d_out, int out_size, void* d_ws, size_t ws_size,
                              hipStream_t stream)
{
    (void)in_sizes; (void)n_in; (void)out_size; (void)ws_size;
    const int*   enc_inp  = (const int*)d_in[0];
    const int*   dec_inp  = (const int*)d_in[1];
    const int*   enc_mask = (const int*)d_in[2];
    const float* tok_emb  = (const float*)d_in[3];
    const float* pos_emb  = (const float*)d_in[4];
    const float* e_wq  = (const float*)d_in[5];
    const float* e_wk  = (const float*)d_in[6];
    const float* e_wv  = (const float*)d_in[7];
    const float* e_wo  = (const float*)d_in[8];
    const float* e_bo  = (const float*)d_in[9];
    const float* dsa_wq = (const float*)d_in[10];
    const float* dsa_wk = (const float*)d_in[11];
    const float* dsa_wv = (const float*)d_in[12];
    const float* dsa_wo = (const float*)d_in[13];
    const float* dsa_bo = (const float*)d_in[14];
    const float* dca_wq = (const float*)d_in[15];
    const float* dca_wk = (const float*)d_in[16];
    const float* dca_wv = (const float*)d_in[17];
    const float* dca_wo = (const float*)d_in[18];
    const float* dca_bo = (const float*)d_in[19];
    const float* e_ln1_g = (const float*)d_in[20];
    const float* e_ln1_b = (const float*)d_in[21];
    const float* e_ln2_g = (const float*)d_in[22];
    const float* e_ln2_b = (const float*)d_in[23];
    const float* d_ln1_g = (const float*)d_in[24];
    const float* d_ln1_b = (const float*)d_in[25];
    const float* d_ln2_g = (const float*)d_in[26];
    const float* d_ln2_b = (const float*)d_in[27];
    const float* d_ln3_g = (const float*)d_in[28];
    const float* d_ln3_b = (const float*)d_in[29];
    const float* e_w1 = (const float*)d_in[30];
    const float* e_b1 = (const float*)d_in[31];
    const float* e_w2 = (const float*)d_in[32];
    const float* e_b2 = (const float*)d_in[33];
    const float* d_w1 = (const float*)d_in[34];
    const float* d_b1 = (const float*)d_in[35];
    const float* d_w2 = (const float*)d_in[36];
    const float* d_b2 = (const float*)d_in[37];
    const float* out_w = (const float*)d_in[38];
    const float* out_b = (const float*)d_in[39];
    float* out = (float*)d_out;

    // -------- workspace carve (bytes) --------
    char* p = (char*)d_ws;
    auto takeB = [&](size_t bytes) { char* r = p; p += (bytes + 255) & ~(size_t)255; return r; };
    float*  x_enc = (float*)takeB(1048576ull * 4);
    float*  x_dec = (float*)takeB(1048576ull * 4);
    bf16_t* h     = (bf16_t*)takeB(1048576ull * 2);
    bf16_t* hk    = (bf16_t*)takeB(1048576ull * 2);
    bf16_t* qkv   = (bf16_t*)takeB(3145728ull * 2);
    bf16_t* vt    = (bf16_t*)takeB(1048576ull * 2);
    bf16_t* ao    = (bf16_t*)takeB(1048576ull * 2);
    bf16_t* xdb   = (bf16_t*)takeB(1048576ull * 2);
    bf16_t* mid   = (bf16_t*)takeB(4194304ull * 2);
    bf16_t* wqkv_t = (bf16_t*)takeB(12ull * 786432 * 2);
    bf16_t* wo_t   = (bf16_t*)takeB(12ull * 262144 * 2);
    bf16_t* w1_t   = (bf16_t*)takeB(8ull * 1048576 * 2);
    bf16_t* w2_t   = (bf16_t*)takeB(8ull * 1048576 * 2);
    bf16_t* outw_t = (bf16_t*)takeB(16384000ull * 2);

    dim3 blk(256);
    const long LQKV = 1536L * Cdim;

    // ================= weight prep (5 launches) =================
    QkvSrc qs;
    qs.p[0] = e_wq;   qs.p[1] = e_wk;   qs.p[2] = e_wv;
    qs.p[3] = dsa_wq; qs.p[4] = dsa_wk; qs.p[5] = dsa_wv;
    qs.p[6] = dca_wq; qs.p[7] = dca_wk; qs.p[8] = dca_wv;
    tcvt_qkv_k<<<dim3(1, 8, 288), blk, 0, stream>>>(qs, wqkv_t);
    Ptr3 pw;
    pw.p[0] = e_wo; pw.p[1] = dsa_wo; pw.p[2] = dca_wo;
    tcvt_b_k<<<dim3(8, 8, 12), blk, 0, stream>>>(pw, wo_t, Cdim, Cdim, 4, (long)Cdim * Cdim);
    pw.p[0] = e_w1; pw.p[1] = d_w1; pw.p[2] = nullptr;
    tcvt_b_k<<<dim3(32, 8, 8), blk, 0, stream>>>(pw, w1_t, Cdim, FF, 4, (long)Cdim * FF);
    pw.p[0] = e_w2; pw.p[1] = d_w2; pw.p[2] = nullptr;
    tcvt_b_k<<<dim3(8, 32, 8), blk, 0, stream>>>(pw, w2_t, FF, Cdim, 4, (long)FF * Cdim);
    pw.p[0] = out_w; pw.p[1] = nullptr; pw.p[2] = nullptr;
    tcvt_b_k<<<dim3(500, 8, 1), blk, 0, stream>>>(pw, outw_t, Cdim, Vn, 1, 0);

    // ================= encoder =================
    embed_ln_k<<<NTOK / 4, blk, 0, stream>>>(enc_inp, tok_emb, pos_emb, e_ln1_g, e_ln1_b, x_enc, h);
    for (int l = 0; l < Ld; l++) {
        if (l) ln_k<<<NTOK / 4, blk, 0, stream>>>(x_enc, e_ln1_g + l * Cdim, e_ln1_b + l * Cdim, h);
        run_attn(stream, h, h,
                 wqkv_t + (long)l * LQKV, e_bo + l * Cdim, wo_t + (long)l * Cdim * Cdim,
                 x_enc, enc_mask, /*causal=*/false, qkv, vt, ao);
        ln_k<<<NTOK / 4, blk, 0, stream>>>(x_enc, e_ln2_g + l * Cdim, e_ln2_b + l * Cdim, h);
        mgemm_k<128,128,64,true,true,false,true,false,0,false,true><<<dim3(16, 16, 1), blk, 0, stream>>>(
            h, h, 1 << 30, w1_t + (long)l * Cdim * FF, e_b1 + l * FF, nullptr, mid,
            nullptr, nullptr, 1 << 30, Cdim, Cdim, Cdim, FF);
        mgemm_k<64,64,64,true,false,true,false,false,0,false,true><<<dim3(8, 32, 1), blk, 0, stream>>>(
            mid, mid, 1 << 30, w2_t + (long)l * FF * Cdim, e_b2 + l * Cdim, x_enc, x_enc,
            nullptr, nullptr, 1 << 30, FF, FF, FF, Cdim);
    }
    // x_enc now holds enc_out

    // ================= decoder =================
    embed_ln_k<<<NTOK / 4, blk, 0, stream>>>(dec_inp, tok_emb, pos_emb, d_ln1_g, d_ln1_b, x_dec, h);
    for (int l = 0; l < Ld; l++) {
        // causal self-attention
        if (l) ln_k<<<NTOK / 4, blk, 0, stream>>>(x_dec, d_ln1_g + l * Cdim, d_ln1_b + l * Cdim, h);
        run_attn(stream, h, h,
                 wqkv_t + (long)(Ld + l) * LQKV, dsa_bo + l * Cdim,
                 wo_t + (long)(Ld + l) * Cdim * Cdim,
                 x_dec, nullptr, /*causal=*/true, qkv, vt, ao);
        // cross-attention (same LN applied to x and enc_out) — one fused launch
        ln2_k<<<2 * NTOK / 4, blk, 0, stream>>>(x_dec, x_enc,
            d_ln2_g + l * Cdim, d_ln2_b + l * Cdim, h, hk);
        run_attn(stream, h, hk,
                 wqkv_t + (long)(2 * Ld + l) * LQKV, dca_bo + l * Cdim,
                 wo_t + (long)(2 * Ld + l) * Cdim * Cdim,
                 x_dec, enc_mask, /*causal=*/false, qkv, vt, ao);
        // FFN
        ln_k<<<NTOK / 4, blk, 0, stream>>>(x_dec, d_ln3_g + l * Cdim, d_ln3_b + l * Cdim, h);
        mgemm_k<128,128,64,true,true,false,true,false,0,false,true><<<dim3(16, 16, 1), blk, 0, stream>>>(
            h, h, 1 << 30, w1_t + (long)(Ld + l) * Cdim * FF, d_b1 + l * FF, nullptr, mid,
            nullptr, nullptr, 1 << 30, Cdim, Cdim, Cdim, FF);
        if (l < Ld - 1)
            mgemm_k<64,64,64,true,false,true,false,false,0,false,true><<<dim3(8, 32, 1), blk, 0, stream>>>(
                mid, mid, 1 << 30, w2_t + (long)(Ld + l) * FF * Cdim, d_b2 + l * Cdim, x_dec, x_dec,
                nullptr, nullptr, 1 << 30, FF, FF, FF, Cdim);
        else  // last layer: also emit bf16 copy for logits GEMM
            mgemm_k<64,64,64,true,false,true,false,false,0,true,true><<<dim3(8, 32, 1), blk, 0, stream>>>(
                mid, mid, 1 << 30, w2_t + (long)(Ld + l) * FF * Cdim, d_b2 + l * Cdim, x_dec, x_dec,
                xdb, nullptr, 1 << 30, FF, FF, FF, Cdim);
    }

    // ================= final logits (f32 out, 128x128, coalesced, XCD-swizzled) ==========
    mgemm_k<128,128,64,true,false,false,false,false,16,false,true><<<dim3(250, 16, 1), blk, 0, stream>>>(
        xdb, xdb, 1 << 30, outw_t, out_b, nullptr, out, nullptr, nullptr, 1 << 30,
        Cdim, Cdim, Cdim, Vn);
}

// Round 8
// 1005.119 us; speedup vs baseline: 1.3502x; 1.1135x over previous
//
#include <hip/hip_runtime.h>
#include <hip/hip_bf16.h>
#include <math.h>

#define Cdim 512
#define Hn   8
#define HDim 64
#define Ld   4
#define Tn   1024
#define Bn   2
#define NTOK 2048   // B*T
#define FF   2048   // 4*C
#define Vn   32000

typedef __bf16 bf16_t;
typedef __bf16 bf16x8 __attribute__((ext_vector_type(8)));
typedef __bf16 bf16x4 __attribute__((ext_vector_type(4)));
typedef float  f32x4  __attribute__((ext_vector_type(4)));

// ---------------- layernorm: one wave per row, 4 rows/block, no barriers ----------------
__device__ __forceinline__ void ln_wave(const float* __restrict__ xr,
    const float* __restrict__ g, const float* __restrict__ bb,
    bf16_t* __restrict__ yr, int lane)
{
    f32x4 a = *(const f32x4*)&xr[lane * 8];
    f32x4 c = *(const f32x4*)&xr[lane * 8 + 4];
    float s = a[0] + a[1] + a[2] + a[3] + c[0] + c[1] + c[2] + c[3];
    #pragma unroll
    for (int o = 1; o < 64; o <<= 1) s += __shfl_xor(s, o, 64);
    float mean = s * (1.f / Cdim);
    float d[8], qv = 0.f;
    #pragma unroll
    for (int k = 0; k < 4; k++) { d[k] = a[k] - mean; d[4 + k] = c[k] - mean; }
    #pragma unroll
    for (int k = 0; k < 8; k++) qv += d[k] * d[k];
    #pragma unroll
    for (int o = 1; o < 64; o <<= 1) qv += __shfl_xor(qv, o, 64);
    float inv = rsqrtf(qv * (1.f / Cdim) + 1e-5f);
    f32x4 g0 = *(const f32x4*)&g[lane * 8],  g1 = *(const f32x4*)&g[lane * 8 + 4];
    f32x4 b0 = *(const f32x4*)&bb[lane * 8], b1 = *(const f32x4*)&bb[lane * 8 + 4];
    bf16x8 o;
    #pragma unroll
    for (int k = 0; k < 4; k++) {
        o[k]     = (bf16_t)(d[k]     * inv * g0[k] + b0[k]);
        o[4 + k] = (bf16_t)(d[4 + k] * inv * g1[k] + b1[k]);
    }
    *(bf16x8*)&yr[lane * 8] = o;
}

__global__ __launch_bounds__(256) void ln_k(const float* __restrict__ x,
    const float* __restrict__ g, const float* __restrict__ bb, bf16_t* __restrict__ y)
{
    int wid = threadIdx.x >> 6, lane = threadIdx.x & 63;
    int row = blockIdx.x * 4 + wid;
    ln_wave(x + (long)row * Cdim, g, bb, y + (long)row * Cdim, lane);
}

// two-source LN (cross-attention): rows < NTOK from x1->y1, else x2->y2 (same g,b)
__global__ __launch_bounds__(256) void ln2_k(const float* __restrict__ x1,
    const float* __restrict__ x2, const float* __restrict__ g,
    const float* __restrict__ bb, bf16_t* __restrict__ y1, bf16_t* __restrict__ y2)
{
    int wid = threadIdx.x >> 6, lane = threadIdx.x & 63;
    int row = blockIdx.x * 4 + wid;
    const float* x = (row < NTOK) ? x1 : x2;
    bf16_t*      y = (row < NTOK) ? y1 : y2;
    int r = row & (NTOK - 1);
    ln_wave(x + (long)r * Cdim, g, bb, y + (long)r * Cdim, lane);
}

// ---------------- fused embedding + first-layer LN (wave per row) ----------------
__global__ __launch_bounds__(256) void embed_ln_k(const int* __restrict__ inp,
    const float* __restrict__ tok, const float* __restrict__ pos,
    const float* __restrict__ g, const float* __restrict__ bb,
    float* __restrict__ x, bf16_t* __restrict__ y)
{
    int wid = threadIdx.x >> 6, lane = threadIdx.x & 63;
    int bt = blockIdx.x * 4 + wid;
    int t = bt & (Tn - 1);
    long toff = (long)inp[bt] * Cdim;
    f32x4 a = *(const f32x4*)&tok[toff + lane * 8];
    f32x4 c = *(const f32x4*)&tok[toff + lane * 8 + 4];
    f32x4 pa = *(const f32x4*)&pos[(long)t * Cdim + lane * 8];
    f32x4 pc = *(const f32x4*)&pos[(long)t * Cdim + lane * 8 + 4];
    a += pa; c += pc;
    float* xr = x + (long)bt * Cdim;
    *(f32x4*)&xr[lane * 8] = a;
    *(f32x4*)&xr[lane * 8 + 4] = c;
    float s = a[0] + a[1] + a[2] + a[3] + c[0] + c[1] + c[2] + c[3];
    #pragma unroll
    for (int o = 1; o < 64; o <<= 1) s += __shfl_xor(s, o, 64);
    float mean = s * (1.f / Cdim);
    float d[8], qv = 0.f;
    #pragma unroll
    for (int k = 0; k < 4; k++) { d[k] = a[k] - mean; d[4 + k] = c[k] - mean; }
    #pragma unroll
    for (int k = 0; k < 8; k++) qv += d[k] * d[k];
    #pragma unroll
    for (int o = 1; o < 64; o <<= 1) qv += __shfl_xor(qv, o, 64);
    float inv = rsqrtf(qv * (1.f / Cdim) + 1e-5f);
    f32x4 g0 = *(const f32x4*)&g[lane * 8],  g1 = *(const f32x4*)&g[lane * 8 + 4];
    f32x4 b0 = *(const f32x4*)&bb[lane * 8], b1 = *(const f32x4*)&bb[lane * 8 + 4];
    bf16x8 o;
    #pragma unroll
    for (int k = 0; k < 4; k++) {
        o[k]     = (bf16_t)(d[k]     * inv * g0[k] + b0[k]);
        o[4 + k] = (bf16_t)(d[4 + k] * inv * g1[k] + b1[k]);
    }
    *(bf16x8*)&y[(long)bt * Cdim + lane * 8] = o;
}

// ------- batched tiled transpose+convert: f32 [R,Cc] -> bf16 [Cc,R] over z sources/layers -------
struct Ptr3 { const float* p[3]; };
__global__ __launch_bounds__(256) void tcvt_b_k(Ptr3 srcs, bf16_t* __restrict__ dst,
    int R, int Cc, int lps, long dstStride)
{
    int z = blockIdx.z; int s = z / lps, l = z - s * lps;
    const float* in = srcs.p[s] + (long)l * R * Cc;
    bf16_t* op = dst + (long)z * dstStride;
    __shared__ float t[64][65];
    int r0 = blockIdx.y * 64, c0 = blockIdx.x * 64;
    int tx = threadIdx.x & 63, ty = threadIdx.x >> 6;
    #pragma unroll
    for (int i = 0; i < 16; i++)
        t[ty + i * 4][tx] = in[(long)(r0 + ty + i * 4) * Cc + c0 + tx];
    __syncthreads();
    #pragma unroll
    for (int i = 0; i < 16; i++) {
        int cc = ty + i * 4;
        op[(long)(c0 + cc) * R + r0 + tx] = (bf16_t)t[tx][cc];
    }
}

// ------- fused QKV weight prep: 9 (set,part) sources in one launch -------
struct QkvSrc { const float* p[9]; };
__global__ __launch_bounds__(256) void tcvt_qkv_k(QkvSrc srcs, bf16_t* __restrict__ outp)
{
    int z = blockIdx.z;
    int si = z >> 5, zb = (z >> 3) & 3, zh = z & 7;
    int set = si / 3, part = si - set * 3;
    const float* in = srcs.p[si] + (long)zb * (Hn * Cdim * HDim) + (long)zh * (Cdim * HDim);
    bf16_t* op = outp + ((long)set * Ld + zb) * (1536L * Cdim)
                      + (long)part * 512 * Cdim + (long)zh * 64 * Cdim;
    __shared__ float t[64][65];
    int r0 = blockIdx.y * 64;
    int tx = threadIdx.x & 63, ty = threadIdx.x >> 6;
    #pragma unroll
    for (int i = 0; i < 16; i++)
        t[ty + i * 4][tx] = in[(long)(r0 + ty + i * 4) * HDim + tx];
    __syncthreads();
    #pragma unroll
    for (int i = 0; i < 16; i++) {
        int cc = ty + i * 4;
        op[(long)cc * Cdim + r0 + tx] = (bf16_t)t[tx][cc];
    }
}

// ================= bf16 MFMA GEMM, double-buffered K pipeline =================
// 256 threads = 4 waves (2x2). Chunk-XOR LDS swizzle (conflict-free reads).
// Separate As0/As1/Bs0/Bs1 arrays (compile-time distinct objects) so the
// in-flight global_load_lds of the next tile provably doesn't alias the
// ds_reads of the current tile -> stage latency hides under MFMA.
template<int BM, int BN, int BK, bool BIAS, bool RELU, bool RES, bool OBF,
         bool VOUT, int SWZM, bool XOUT, bool COAL>
__global__ __launch_bounds__(256) void mgemm_k(
    const bf16_t* __restrict__ A, const bf16_t* __restrict__ A2, int aSplit,
    const bf16_t* __restrict__ Bt, const float* __restrict__ bias,
    const float* __restrict__ res, void* __restrict__ Cout,
    bf16_t* __restrict__ xout, bf16_t* __restrict__ vtout, int vSplit,
    int K, int lda, int ldb, int ldc)
{
    constexpr int MR = BM / 32;
    constexpr int NR = BN / 32;
    constexpr int KK = BK / 32;
    constexpr int LPR = BK / 8;
    __shared__ bf16_t As0[BM * BK];
    __shared__ bf16_t As1[BM * BK];
    __shared__ bf16_t Bs0[BN * BK];
    __shared__ bf16_t Bs1[BN * BK];
    __shared__ float cws[COAL ? 4 * 16 * 36 : 1];

    int tid = threadIdx.x;
    int wv = tid >> 6, lane = tid & 63;
    int bm, bn;
    if constexpr (SWZM > 0) {
        int lin = blockIdx.y * gridDim.x + blockIdx.x;
        int tot = gridDim.x * gridDim.y;
        int chunk = tot >> 3;
        int e = (lin & 7) * chunk + (lin >> 3);
        bm = (e % SWZM) * BM;
        bn = (e / SWZM) * BN;
    } else {
        bm = blockIdx.y * BM; bn = blockIdx.x * BN;
    }
    const bf16_t* Ab = (bn < aSplit) ? A : A2;
    int wr = wv >> 1, wc = wv & 1;

    f32x4 acc[MR][NR];
    #pragma unroll
    for (int i = 0; i < MR; i++)
        #pragma unroll
        for (int j = 0; j < NR; j++)
            acc[i][j] = (f32x4){0.f, 0.f, 0.f, 0.f};

    constexpr int RPW = 512 / BK;
    constexpr int RPP = 2048 / BK;
    const int sr  = lane / LPR;
    const int sc8 = ((lane % LPR) ^ (sr & (LPR - 1))) * 8;
    const int r16 = lane & 15, g4 = lane >> 4;

    auto stage = [&](int k0, bf16_t (&Asb)[BM * BK], bf16_t (&Bsb)[BN * BK]) {
        #pragma unroll
        for (int p = 0; p < BM * BK / 2048; p++) {
            int rb = p * RPP + wv * RPW;
            const bf16_t* g = Ab + (long)(bm + rb + sr) * lda + (k0 + sc8);
            __builtin_amdgcn_global_load_lds(
                (const __attribute__((address_space(1))) void*)g,
                (__attribute__((address_space(3))) void*)&Asb[rb * BK],
                16, 0, 0);
        }
        #pragma unroll
        for (int p = 0; p < BN * BK / 2048; p++) {
            int rb = p * RPP + wv * RPW;
            const bf16_t* g = Bt + (long)(bn + rb + sr) * ldb + (k0 + sc8);
            __builtin_amdgcn_global_load_lds(
                (const __attribute__((address_space(1))) void*)g,
                (__attribute__((address_space(3))) void*)&Bsb[rb * BK],
                16, 0, 0);
        }
    };
    auto compute = [&](bf16_t (&Asb)[BM * BK], bf16_t (&Bsb)[BN * BK]) {
        #pragma unroll
        for (int kk = 0; kk < KK; kk++) {
            bf16x8 bkk[NR];
            #pragma unroll
            for (int j = 0; j < NR; j++) {
                int row = wc * (BN / 2) + j * 16 + r16;
                bkk[j] = *(const bf16x8*)&Bsb[row * BK + (((kk * 4 + g4) ^ (row & (LPR - 1))) * 8)];
            }
            #pragma unroll
            for (int i = 0; i < MR; i++) {
                int row = wr * (BM / 2) + i * 16 + r16;
                bf16x8 a = *(const bf16x8*)&Asb[row * BK + (((kk * 4 + g4) ^ (row & (LPR - 1))) * 8)];
                #pragma unroll
                for (int j = 0; j < NR; j++)
                    acc[i][j] = __builtin_amdgcn_mfma_f32_16x16x32_bf16(a, bkk[j], acc[i][j], 0, 0, 0);
            }
        }
    };

    int nIt = K / BK;
    stage(0, As0, Bs0);
    for (int it = 0; it < nIt; it += 2) {
        __syncthreads();                               // As0/Bs0 staged; prior reads done
        if (it + 1 < nIt) stage((it + 1) * BK, As1, Bs1);
        compute(As0, Bs0);
        __syncthreads();                               // As1/Bs1 staged; As0 reads done
        if (it + 2 < nIt) stage((it + 2) * BK, As0, Bs0);
        if (it + 1 < nIt) compute(As1, Bs1);
    }

    if constexpr (COAL) {
        // ---- coalesced epilogue via per-wave LDS bounce (no barriers needed) ----
        #pragma unroll
        for (int i = 0; i < MR; i++) {
            int gr0 = bm + wr * (BM / 2) + i * 16;
            #pragma unroll
            for (int hh = 0; hh < NR / 2; hh++) {
                #pragma unroll
                for (int jj = 0; jj < 2; jj++) {
                    int j = hh * 2 + jj;
                    int gc = bn + wc * (BN / 2) + j * 16 + r16;
                    float bv = BIAS ? bias[gc] : 0.f;
                    #pragma unroll
                    for (int q = 0; q < 4; q++) {
                        float v = acc[i][j][q];
                        if (BIAS) v += bv;
                        if (RELU) v = fmaxf(v, 0.f);
                        cws[(wv * 16 + g4 * 4 + q) * 36 + jj * 16 + r16] = v;
                    }
                }
                int gcb = bn + wc * (BN / 2) + hh * 32;
                if constexpr (OBF) {
                    int row = lane >> 2, c8 = (lane & 3) * 8;
                    f32x4 v0 = *(f32x4*)&cws[(wv * 16 + row) * 36 + c8];
                    f32x4 v1 = *(f32x4*)&cws[(wv * 16 + row) * 36 + c8 + 4];
                    long oidx = (long)(gr0 + row) * ldc + gcb + c8;
                    bf16x8 o;
                    #pragma unroll
                    for (int k = 0; k < 4; k++) { o[k] = (bf16_t)v0[k]; o[4 + k] = (bf16_t)v1[k]; }
                    *(bf16x8*)&((bf16_t*)Cout)[oidx] = o;
                } else {
                    #pragma unroll
                    for (int ps = 0; ps < 2; ps++) {
                        int row = (lane >> 3) + 8 * ps, c4 = (lane & 7) * 4;
                        f32x4 v = *(f32x4*)&cws[(wv * 16 + row) * 36 + c4];
                        long oidx = (long)(gr0 + row) * ldc + gcb + c4;
                        if (RES) v += *(const f32x4*)&res[oidx];
                        *(f32x4*)&((float*)Cout)[oidx] = v;
                        if (XOUT) {
                            bf16x4 o;
                            #pragma unroll
                            for (int k = 0; k < 4; k++) o[k] = (bf16_t)v[k];
                            *(bf16x4*)&xout[oidx] = o;
                        }
                    }
                }
            }
        }
    } else {
        // ---- scalar epilogue (VOUT scatter path) ----
        #pragma unroll
        for (int i = 0; i < MR; i++) {
            #pragma unroll
            for (int j = 0; j < NR; j++) {
                int gr = bm + wr * (BM / 2) + i * 16 + g4 * 4;
                int gc = bn + wc * (BN / 2) + j * 16 + r16;
                float bv = BIAS ? bias[gc] : 0.f;
                #pragma unroll
                for (int q = 0; q < 4; q++) {
                    float v = acc[i][j][q];
                    if (BIAS) v += bv;
                    if (RELU) v = fmaxf(v, 0.f);
                    if (VOUT && gc >= vSplit) {
                        int row = gr + q;
                        int b = row >> 10, t = row & (Tn - 1);
                        vtout[((long)b * 512 + (gc - vSplit)) * Tn + t] = (bf16_t)v;
                    } else {
                        long oidx = (long)(gr + q) * ldc + gc;
                        if (RES)  v += res[oidx];
                        if (OBF) ((bf16_t*)Cout)[oidx] = (bf16_t)v;
                        else     ((float*) Cout)[oidx] = v;
                        if (XOUT) xout[oidx] = (bf16_t)v;
                    }
                }
            }
        }
    }
}

// ================= fused flash attention (8 waves, KV-split, dbuf LDS, 1 barrier/iter) =========
template<bool CAUSAL, bool HASMASK>
__global__ __launch_bounds__(512, 2) void flash_k(
    const bf16_t* __restrict__ qkv, const bf16_t* __restrict__ vt,
    const int* __restrict__ mask, bf16_t* __restrict__ ao)
{
    __shared__ bf16_t Kl[2][2][64][72];
    __shared__ bf16_t Vl[2][2][64][72];
    __shared__ bf16_t Pl[8][16][72];

    int qt = blockIdx.x, bh = blockIdx.y;
    int b = bh >> 3, h = bh & 7;
    int tid = threadIdx.x, wv = tid >> 6, lane = tid & 63;
    int wg = wv >> 2, wq4 = wv & 3;
    int r16 = lane & 15, g4 = lane >> 4;
    int gtid = tid & 255;

    const bf16_t* qb = qkv + ((long)(b * Tn + qt * 64 + wq4 * 16 + r16)) * 1536 + h * 64;
    bf16x8 aq0 = *(const bf16x8*)&qb[g4 * 8];
    bf16x8 aq1 = *(const bf16x8*)&qb[32 + g4 * 8];

    f32x4 acc[4];
    #pragma unroll
    for (int j = 0; j < 4; j++) acc[j] = (f32x4){0.f, 0.f, 0.f, 0.f};
    float m_[4], l_[4];
    #pragma unroll
    for (int q = 0; q < 4; q++) { m_[q] = -1e30f; l_[q] = 0.f; }

    int lastT = CAUSAL ? qt : (Tn / 64 - 1);
    int niter = CAUSAL ? (qt / 2 + 1) : (Tn / 128);
    int krow = gtid >> 3, kcol = (gtid & 7) * 8;

    // prologue prefetch (it = 0)
    bf16x8 kr[2], vr[2];
    int mv = 0;
    {
        int t0 = wg;
        if (t0 <= lastT) {
            int s0 = t0 * 64;
            #pragma unroll
            for (int i = 0; i < 2; i++)
                kr[i] = *(const bf16x8*)&qkv[((long)(b * Tn + s0 + krow + i * 32)) * 1536 + 512 + h * 64 + kcol];
            #pragma unroll
            for (int i = 0; i < 2; i++)
                vr[i] = *(const bf16x8*)&vt[((long)(bh * 64 + krow + i * 32)) * Tn + s0 + kcol];
            if (HASMASK) mv = mask[b * Tn + s0 + lane];
        }
    }

    for (int it = 0; it < niter; it++) {
        int cur = it & 1;
        int t = 2 * it + wg;
        bool active = t <= lastT;
        if (active) {
            #pragma unroll
            for (int i = 0; i < 2; i++) *(bf16x8*)&Kl[cur][wg][krow + i * 32][kcol] = kr[i];
            #pragma unroll
            for (int i = 0; i < 2; i++) *(bf16x8*)&Vl[cur][wg][krow + i * 32][kcol] = vr[i];
        }
        int mv_use = mv;
        __syncthreads();                      // tiles visible (prior reads were pre-barrier(it-1))
        // ---- prefetch next tile: in flight across this iteration's compute ----
        int tn = t + 2;
        if (it + 1 < niter && tn <= lastT) {
            int sn = tn * 64;
            #pragma unroll
            for (int i = 0; i < 2; i++)
                kr[i] = *(const bf16x8*)&qkv[((long)(b * Tn + sn + krow + i * 32)) * 1536 + 512 + h * 64 + kcol];
            #pragma unroll
            for (int i = 0; i < 2; i++)
                vr[i] = *(const bf16x8*)&vt[((long)(bh * 64 + krow + i * 32)) * Tn + sn + kcol];
            if (HASMASK) mv = mask[b * Tn + sn + lane];
        }
        if (!active) continue;

        // ---- QK^T: 8 MFMA ----
        f32x4 scv[4];
        __builtin_amdgcn_s_setprio(1);
        #pragma unroll
        for (int j = 0; j < 4; j++) {
            scv[j] = (f32x4){0.f, 0.f, 0.f, 0.f};
            bf16x8 bk0 = *(const bf16x8*)&Kl[cur][wg][j * 16 + r16][g4 * 8];
            bf16x8 bk1 = *(const bf16x8*)&Kl[cur][wg][j * 16 + r16][32 + g4 * 8];
            scv[j] = __builtin_amdgcn_mfma_f32_16x16x32_bf16(aq0, bk0, scv[j], 0, 0, 0);
            scv[j] = __builtin_amdgcn_mfma_f32_16x16x32_bf16(aq1, bk1, scv[j], 0, 0, 0);
        }
        __builtin_amdgcn_s_setprio(0);

        // ---- scale + mask ----
        bool diag = CAUSAL && (t == qt);
        #pragma unroll
        for (int j = 0; j < 4; j++) {
            int col = j * 16 + r16;
            int mm = 1;
            if (HASMASK) mm = __shfl(mv_use, col, 64);
            #pragma unroll
            for (int q = 0; q < 4; q++) {
                float v = scv[j][q] * 0.125f;
                if (diag && col > wq4 * 16 + g4 * 4 + q) v = -1e30f;
                if (HASMASK && mm == 0) v = -1e30f;
                scv[j][q] = v;
            }
        }

        // ---- online softmax with defer-max (THR=8) ----
        float pmax[4];
        #pragma unroll
        for (int q = 0; q < 4; q++) {
            float v = fmaxf(fmaxf(scv[0][q], scv[1][q]), fmaxf(scv[2][q], scv[3][q]));
            v = fmaxf(v, __shfl_xor(v, 1, 64));
            v = fmaxf(v, __shfl_xor(v, 2, 64));
            v = fmaxf(v, __shfl_xor(v, 4, 64));
            v = fmaxf(v, __shfl_xor(v, 8, 64));
            pmax[q] = v;
        }
        bool skip = __all(pmax[0] <= m_[0] + 8.f && pmax[1] <= m_[1] + 8.f &&
                          pmax[2] <= m_[2] + 8.f && pmax[3] <= m_[3] + 8.f);
        if (!skip) {
            #pragma unroll
            for (int q = 0; q < 4; q++) {
                float mnew = fmaxf(m_[q], pmax[q]);
                float rf = __expf(m_[q] - mnew);
                l_[q] *= rf;
                #pragma unroll
                for (int j = 0; j < 4; j++) acc[j][q] *= rf;
                m_[q] = mnew;
            }
        }
        #pragma unroll
        for (int q = 0; q < 4; q++) {
            float rs = 0.f;
            #pragma unroll
            for (int j = 0; j < 4; j++) {
                float pv = __expf(scv[j][q] - m_[q]);
                scv[j][q] = pv;
                rs += pv;
            }
            rs += __shfl_xor(rs, 1, 64);
            rs += __shfl_xor(rs, 2, 64);
            rs += __shfl_xor(rs, 4, 64);
            rs += __shfl_xor(rs, 8, 64);
            l_[q] += rs;
        }

        // ---- P -> per-wave LDS (C/D layout -> A-frag layout) ----
        #pragma unroll
        for (int j = 0; j < 4; j++)
            #pragma unroll
            for (int q = 0; q < 4; q++)
                Pl[wv][g4 * 4 + q][j * 16 + r16] = (bf16_t)scv[j][q];
        asm volatile("s_waitcnt lgkmcnt(0)" ::: "memory");
        __builtin_amdgcn_sched_barrier(0);

        // ---- PV: 8 MFMA ----
        __builtin_amdgcn_s_setprio(1);
        #pragma unroll
        for (int c = 0; c < 2; c++) {
            bf16x8 pa = *(const bf16x8*)&Pl[wv][r16][c * 32 + g4 * 8];
            #pragma unroll
            for (int j = 0; j < 4; j++) {
                bf16x8 bv = *(const bf16x8*)&Vl[cur][wg][j * 16 + r16][c * 32 + g4 * 8];
                acc[j] = __builtin_amdgcn_mfma_f32_16x16x32_bf16(pa, bv, acc[j], 0, 0, 0);
            }
        }
        __builtin_amdgcn_s_setprio(0);
    }

    // ---- merge group 1 state into group 0 via LDS, write output ----
    float* accS = (float*)&Kl[0][0][0][0];
    float* mlS  = accS + 64 * 64;
    __syncthreads();
    if (wg == 1) {
        #pragma unroll
        for (int j = 0; j < 4; j++)
            #pragma unroll
            for (int q = 0; q < 4; q++)
                accS[(wq4 * 16 + g4 * 4 + q) * 64 + j * 16 + r16] = acc[j][q];
        if (r16 == 0)
            #pragma unroll
            for (int q = 0; q < 4; q++) {
                mlS[(wq4 * 16 + g4 * 4 + q) * 2 + 0] = m_[q];
                mlS[(wq4 * 16 + g4 * 4 + q) * 2 + 1] = l_[q];
            }
    }
    __syncthreads();
    if (wg == 0) {
        bf16_t* aob = ao + ((long)(b * Tn + qt * 64 + wq4 * 16 + g4 * 4)) * Cdim + h * 64;
        #pragma unroll
        for (int q = 0; q < 4; q++) {
            int row = wq4 * 16 + g4 * 4 + q;
            float mB = mlS[row * 2], lB = mlS[row * 2 + 1];
            float mS = fmaxf(m_[q], mB);
            float fA = __expf(m_[q] - mS), fB = __expf(mB - mS);
            float lS = l_[q] * fA + lB * fB;
            float inv = 1.f / lS;
            #pragma unroll
            for (int j = 0; j < 4; j++) {
                float o = (acc[j][q] * fA + accS[row * 64 + j * 16 + r16] * fB) * inv;
                aob[(long)q * Cdim + j * 16 + r16] = (bf16_t)o;
            }
        }
    }
}

// ================================ host orchestration ================================
static void run_attn(hipStream_t stream, const bf16_t* hq, const bf16_t* hkv,
    const bf16_t* wqkv, const float* bo, const bf16_t* wo_t,
    float* xres, const int* mask, bool causal,
    bf16_t* qkv, bf16_t* vt, bf16_t* ao)
{
    dim3 blk(256);
    // fused qkv projection: N=1536 (cols<512 read hq, else hkv); v-part -> vt
    mgemm_k<64,128,64,false,false,false,true,true,0,false,false><<<dim3(12, 32, 1), blk, 0, stream>>>(
        hq, hkv, 512, wqkv, nullptr, nullptr, qkv, nullptr, vt, 1024,
        Cdim, Cdim, Cdim, 1536);
    if (causal)
        flash_k<true,false><<<dim3(Tn / 64, Bn * Hn), dim3(512), 0, stream>>>(qkv, vt, nullptr, ao);
    else
        flash_k<false,true><<<dim3(Tn / 64, Bn * Hn), dim3(512), 0, stream>>>(qkv, vt, mask, ao);
    // out projection + bias + residual (f32, in place on xres) — coalesced epilogue
    mgemm_k<64,64,64,true,false,true,false,false,0,false,true><<<dim3(8, 32, 1), blk, 0, stream>>>(
        ao, ao, 1 << 30, wo_t, bo, xres, xres, nullptr, nullptr, 1 << 30,
        Cdim, Cdim, Cdim, Cdim);
}

extern "C" void kernel_launch(void* const* d_in, const int* in_sizes, int n_in,
                              void* d_out, int out_size, void* d_ws, size_t ws_size,
                              hipStream_t stream)
{
    (void)in_sizes; (void)n_in; (void)out_size; (void)ws_size;
    const int*   enc_inp  = (const int*)d_in[0];
    const int*   dec_inp  = (const int*)d_in[1];
    const int*   enc_mask = (const int*)d_in[2];
    const float* tok_emb  = (const float*)d_in[3];
    const float* pos_emb  = (const float*)d_in[4];
    const float* e_wq  = (const float*)d_in[5];
    const float* e_wk  = (const float*)d_in[6];
    const float* e_wv  = (const float*)d_in[7];
    const float* e_wo  = (const float*)d_in[8];
    const float* e_bo  = (const float*)d_in[9];
    const float* dsa_wq = (const float*)d_in[10];
    const float* dsa_wk = (const float*)d_in[11];
    const float* dsa_wv = (const float*)d_in[12];
    const float* dsa_wo = (const float*)d_in[13];
    const float* dsa_bo = (const float*)d_in[14];
    const float* dca_wq = (const float*)d_in[15];
    const float* dca_wk = (const float*)d_in[16];
    const float* dca_wv = (const float*)d_in[17];
    const float* dca_wo = (const float*)d_in[18];
    const float* dca_bo = (const float*)d_in[19];
    const float* e_ln1_g = (const float*)d_in[20];
    const float* e_ln1_b = (const float*)d_in[21];
    const float* e_ln2_g = (const float*)d_in[22];
    const float* e_ln2_b = (const float*)d_in[23];
    const float* d_ln1_g = (const float*)d_in[24];
    const float* d_ln1_b = (const float*)d_in[25];
    const float* d_ln2_g = (const float*)d_in[26];
    const float* d_ln2_b = (const float*)d_in[27];
    const float* d_ln3_g = (const float*)d_in[28];
    const float* d_ln3_b = (const float*)d_in[29];
    const float* e_w1 = (const float*)d_in[30];
    const float* e_b1 = (const float*)d_in[31];
    const float* e_w2 = (const float*)d_in[32];
    const float* e_b2 = (const float*)d_in[33];
    const float* d_w1 = (const float*)d_in[34];
    const float* d_b1 = (const float*)d_in[35];
    const float* d_w2 = (const float*)d_in[36];
    const float* d_b2 = (const float*)d_in[37];
    const float* out_w = (const float*)d_in[38];
    const float* out_b = (const float*)d_in[39];
    float* out = (float*)d_out;

    // -------- workspace carve (bytes) --------
    char* p = (char*)d_ws;
    auto takeB = [&](size_t bytes) { char* r = p; p += (bytes + 255) & ~(size_t)255; return r; };
    float*  x_enc = (float*)takeB(1048576ull * 4);
    float*  x_dec = (float*)takeB(1048576ull * 4);
    bf16_t* h     = (bf16_t*)takeB(1048576ull * 2);
    bf16_t* hk    = (bf16_t*)takeB(1048576ull * 2);
    bf16_t* qkv   = (bf16_t*)takeB(3145728ull * 2);
    bf16_t* vt    = (bf16_t*)takeB(1048576ull * 2);
    bf16_t* ao    = (bf16_t*)takeB(1048576ull * 2);
    bf16_t* xdb   = (bf16_t*)takeB(1048576ull * 2);
    bf16_t* mid   = (bf16_t*)takeB(4194304ull * 2);
    bf16_t* wqkv_t = (bf16_t*)takeB(12ull * 786432 * 2);
    bf16_t* wo_t   = (bf16_t*)takeB(12ull * 262144 * 2);
    bf16_t* w1_t   = (bf16_t*)takeB(8ull * 1048576 * 2);
    bf16_t* w2_t   = (bf16_t*)takeB(8ull * 1048576 * 2);
    bf16_t* outw_t = (bf16_t*)takeB(16384000ull * 2);

    dim3 blk(256);
    const long LQKV = 1536L * Cdim;

    // ================= weight prep (5 launches) =================
    QkvSrc qs;
    qs.p[0] = e_wq;   qs.p[1] = e_wk;   qs.p[2] = e_wv;
    qs.p[3] = dsa_wq; qs.p[4] = dsa_wk; qs.p[5] = dsa_wv;
    qs.p[6] = dca_wq; qs.p[7] = dca_wk; qs.p[8] = dca_wv;
    tcvt_qkv_k<<<dim3(1, 8, 288), blk, 0, stream>>>(qs, wqkv_t);
    Ptr3 pw;
    pw.p[0] = e_wo; pw.p[1] = dsa_wo; pw.p[2] = dca_wo;
    tcvt_b_k<<<dim3(8, 8, 12), blk, 0, stream>>>(pw, wo_t, Cdim, Cdim, 4, (long)Cdim * Cdim);
    pw.p[0] = e_w1; pw.p[1] = d_w1; pw.p[2] = nullptr;
    tcvt_b_k<<<dim3(32, 8, 8), blk, 0, stream>>>(pw, w1_t, Cdim, FF, 4, (long)Cdim * FF);
    pw.p[0] = e_w2; pw.p[1] = d_w2; pw.p[2] = nullptr;
    tcvt_b_k<<<dim3(8, 32, 8), blk, 0, stream>>>(pw, w2_t, FF, Cdim, 4, (long)FF * Cdim);
    pw.p[0] = out_w; pw.p[1] = nullptr; pw.p[2] = nullptr;
    tcvt_b_k<<<dim3(500, 8, 1), blk, 0, stream>>>(pw, outw_t, Cdim, Vn, 1, 0);

    // ================= encoder =================
    embed_ln_k<<<NTOK / 4, blk, 0, stream>>>(enc_inp, tok_emb, pos_emb, e_ln1_g, e_ln1_b, x_enc, h);
    for (int l = 0; l < Ld; l++) {
        if (l) ln_k<<<NTOK / 4, blk, 0, stream>>>(x_enc, e_ln1_g + l * Cdim, e_ln1_b + l * Cdim, h);
        run_attn(stream, h, h,
                 wqkv_t + (long)l * LQKV, e_bo + l * Cdim, wo_t + (long)l * Cdim * Cdim,
                 x_enc, enc_mask, /*causal=*/false, qkv, vt, ao);
        ln_k<<<NTOK / 4, blk, 0, stream>>>(x_enc, e_ln2_g + l * Cdim, e_ln2_b + l * Cdim, h);
        mgemm_k<128,128,64,true,true,false,true,false,0,false,true><<<dim3(16, 16, 1), blk, 0, stream>>>(
            h, h, 1 << 30, w1_t + (long)l * Cdim * FF, e_b1 + l * FF, nullptr, mid,
            nullptr, nullptr, 1 << 30, Cdim, Cdim, Cdim, FF);
        mgemm_k<64,64,64,true,false,true,false,false,0,false,true><<<dim3(8, 32, 1), blk, 0, stream>>>(
            mid, mid, 1 << 30, w2_t + (long)l * FF * Cdim, e_b2 + l * Cdim, x_enc, x_enc,
            nullptr, nullptr, 1 << 30, FF, FF, FF, Cdim);
    }
    // x_enc now holds enc_out

    // ================= decoder =================
    embed_ln_k<<<NTOK / 4, blk, 0, stream>>>(dec_inp, tok_emb, pos_emb, d_ln1_g, d_ln1_b, x_dec, h);
    for (int l = 0; l < Ld; l++) {
        // causal self-attention
        if (l) ln_k<<<NTOK / 4, blk, 0, stream>>>(x_dec, d_ln1_g + l * Cdim, d_ln1_b + l * Cdim, h);
        run_attn(stream, h, h,
                 wqkv_t + (long)(Ld + l) * LQKV, dsa_bo + l * Cdim,
                 wo_t + (long)(Ld + l) * Cdim * Cdim,
                 x_dec, nullptr, /*causal=*/true, qkv, vt, ao);
        // cross-attention (same LN applied to x and enc_out) — one fused launch
        ln2_k<<<2 * NTOK / 4, blk, 0, stream>>>(x_dec, x_enc,
            d_ln2_g + l * Cdim, d_ln2_b + l * Cdim, h, hk);
        run_attn(stream, h, hk,
                 wqkv_t + (long)(2 * Ld + l) * LQKV, dca_bo + l * Cdim,
                 wo_t + (long)(2 * Ld + l) * Cdim * Cdim,
                 x_dec, enc_mask, /*causal=*/false, qkv, vt, ao);
        // FFN
        ln_k<<<NTOK / 4, blk, 0, stream>>>(x_dec, d_ln3_g + l * Cdim, d_ln3_b + l * Cdim, h);
        mgemm_k<128,128,64,true,true,false,true,false,0,false,true><<<dim3(16, 16, 1), blk, 0, stream>>>(
            h, h, 1 << 30, w1_t + (long)(Ld + l) * Cdim * FF, d_b1 + l * FF, nullptr, mid,
            nullptr, nullptr, 1 << 30, Cdim, Cdim, Cdim, FF);
        if (l < Ld - 1)
            mgemm_k<64,64,64,true,false,true,false,false,0,false,true><<<dim3(8, 32, 1), blk, 0, stream>>>(
                mid, mid, 1 << 30, w2_t + (long)(Ld + l) * FF * Cdim, d_b2 + l * Cdim, x_dec, x_dec,
                nullptr, nullptr, 1 << 30, FF, FF, FF, Cdim);
        else  // last layer: also emit bf16 copy for logits GEMM
            mgemm_k<64,64,64,true,false,true,false,false,0,true,true><<<dim3(8, 32, 1), blk, 0, stream>>>(
                mid, mid, 1 << 30, w2_t + (long)(Ld + l) * FF * Cdim, d_b2 + l * Cdim, x_dec, x_dec,
                xdb, nullptr, 1 << 30, FF, FF, FF, Cdim);
    }

    // ================= final logits (f32 out, 128x128, coalesced, XCD-swizzled) ==========
    mgemm_k<128,128,64,true,false,false,false,false,16,false,true><<<dim3(250, 16, 1), blk, 0, stream>>>(
        xdb, xdb, 1 << 30, outw_t, out_b, nullptr, out, nullptr, nullptr, 1 << 30,
        Cdim, Cdim, Cdim, Vn);
}